// Round 1
// baseline (347.787 us; speedup 1.0000x reference)
//
#include <hip/hip_runtime.h>

// Problem constants (fixed by setup_inputs)
#define B_   4
#define H_   128
#define W_   128
#define L_   (H_*W_)        // 16384
#define C_   128
#define N_   8
#define R_   8
#define LS_  4096           // active scan positions per batch (64x64 top-left region)
#define CS_  16             // scan chunk length (steps)
#define NC_  256            // chunks per (b,c) = LS_/CS_

// ---- workspace layout (in floats) ----
#define OFF_XPROC 0ull
#define OFF_Z     (OFF_XPROC + (size_t)B_*L_*C_)                 // 8388608
#define OFF_BANDS (OFF_Z     + (size_t)B_*L_*C_)                 // bands1: [B][3][64][64][C]
#define OFF_U     (OFF_BANDS + (size_t)B_*3*64*64*C_)            // u  [B][4096][C]
#define OFF_DELTA (OFF_U     + (size_t)B_*LS_*C_)
#define OFF_BS    (OFF_DELTA + (size_t)B_*LS_*C_)                // [B][4096][8]
#define OFF_CS    (OFF_BS    + (size_t)B_*LS_*N_)
#define OFF_DSUM  (OFF_CS    + (size_t)B_*LS_*N_)                // [B][NC][C]
#define OFF_HEND  (OFF_DSUM  + (size_t)B_*NC_*C_)                // [B][NC][C][8]
#define OFF_HIN   (OFF_HEND  + (size_t)B_*NC_*C_*N_)
#define OFF_H11   (OFF_HIN   + (size_t)B_*NC_*C_*N_)             // [B][4096][C]

__device__ __forceinline__ float softplus_f(float x) {
    return (x > 20.f) ? x : log1pf(__expf(x));
}

// ============================================================================
// GEMM: out[M x (NCHUNKS*64)] = in[M x 128] @ w[(NCHUNKS*64) x 128]^T
// tile: 128 rows x 64-col chunks; thread tile 8x4; fp32 VALU (no fp32 MFMA on CDNA4)
// ============================================================================
template<int NCHUNKS, bool EPI>
__global__ __launch_bounds__(256) void k_gemm(const float* __restrict__ in,
        const float* __restrict__ w, float* __restrict__ out0, float* __restrict__ out1,
        const float* __restrict__ bias, const float* __restrict__ resid) {
    __shared__ float xs[128*132];   // xs[k*132 + p]  (k-major, padded: 16B aligned rows)
    __shared__ float wsh[128*68];   // wsh[k*68 + j]
    const int tid = threadIdx.x;
    const size_t p0 = (size_t)blockIdx.x * 128;

    { // stage input tile (transpose to k-major)
        const int pp = tid >> 5, k4 = (tid & 31) << 2;
        #pragma unroll
        for (int i = 0; i < 16; ++i) {
            const int p = pp + (i << 3);
            const float4 v = *(const float4*)(in + (p0 + p)*C_ + k4);
            xs[(k4+0)*132 + p] = v.x;
            xs[(k4+1)*132 + p] = v.y;
            xs[(k4+2)*132 + p] = v.z;
            xs[(k4+3)*132 + p] = v.w;
        }
    }
    const int tx = tid & 15, ty = tid >> 4;
    for (int ch = 0; ch < NCHUNKS; ++ch) {
        if (ch) __syncthreads();
        { // stage weight chunk (64 output rows)
            const int jj = tid >> 5, k4 = (tid & 31) << 2;
            #pragma unroll
            for (int i = 0; i < 8; ++i) {
                const int j = jj + (i << 3);
                const float4 v = *(const float4*)(w + (size_t)(ch*64 + j)*C_ + k4);
                wsh[(k4+0)*68 + j] = v.x;
                wsh[(k4+1)*68 + j] = v.y;
                wsh[(k4+2)*68 + j] = v.z;
                wsh[(k4+3)*68 + j] = v.w;
            }
        }
        __syncthreads();
        float acc[8][4];
        #pragma unroll
        for (int i = 0; i < 8; ++i)
            #pragma unroll
            for (int j = 0; j < 4; ++j) acc[i][j] = 0.f;
        #pragma unroll 4
        for (int k = 0; k < 128; ++k) {
            float a[8], bv[4];
            *(float4*)&a[0] = *(const float4*)&xs[k*132 + tx*8];
            *(float4*)&a[4] = *(const float4*)&xs[k*132 + tx*8 + 4];
            *(float4*)&bv[0] = *(const float4*)&wsh[k*68 + ty*4];
            #pragma unroll
            for (int pi = 0; pi < 8; ++pi)
                #pragma unroll
                for (int j = 0; j < 4; ++j)
                    acc[pi][j] += a[pi] * bv[j];
        }
        const int jg = ch*64 + ty*4;
        float bz[4] = {0.f,0.f,0.f,0.f};
        if constexpr (EPI) { *(float4*)&bz[0] = *(const float4*)(bias + jg); }
        float* op; int col;
        if (jg < 128) { op = out0; col = jg; } else { op = out1; col = jg - 128; }
        #pragma unroll
        for (int pi = 0; pi < 8; ++pi) {
            const size_t row = p0 + tx*8 + pi;
            float4 v;
            v.x = acc[pi][0] + bz[0];
            v.y = acc[pi][1] + bz[1];
            v.z = acc[pi][2] + bz[2];
            v.w = acc[pi][3] + bz[3];
            if constexpr (EPI) {
                const float4 rv = *(const float4*)(resid + row*C_ + col);
                v.x += rv.x; v.y += rv.y; v.z += rv.z; v.w += rv.w;
            }
            *(float4*)(op + row*C_ + col) = v;
        }
    }
}

// ============================================================================
// 2-level Haar DWT: x_proc (B,L,C seq layout) -> bands1 [B][3][64][64][C] and
// compact active-region u [B][4096][C] (the packed 64x64 top-left of h00).
// One block per (b, p, q) level-2 site; threads = channels (coalesced).
// ============================================================================
__global__ __launch_bounds__(128) void k_dwt(const float* __restrict__ xp,
        float* __restrict__ bands, float* __restrict__ u) {
    const int c = threadIdx.x;
    const int bid = blockIdx.x;
    const int b = bid >> 10, p = (bid >> 5) & 31, q = bid & 31;
    float v[4][4];
    const size_t base = (size_t)b * L_ * C_ + c;
    #pragma unroll
    for (int i = 0; i < 4; ++i)
        #pragma unroll
        for (int j = 0; j < 4; ++j)
            v[i][j] = xp[base + (size_t)(((p<<2)+i)*W_ + (q<<2)+j) * C_];
    const size_t bstride = (size_t)64*64*C_;
    float ll[2][2];
    #pragma unroll
    for (int di = 0; di < 2; ++di)
        #pragma unroll
        for (int dj = 0; dj < 2; ++dj) {
            const float a  = v[2*di][2*dj],   bb = v[2*di][2*dj+1];
            const float cc = v[2*di+1][2*dj], dd = v[2*di+1][2*dj+1];
            ll[di][dj]     = (a+bb+cc+dd)*0.5f;
            const float lh = (a+bb-cc-dd)*0.5f;
            const float hl = (a-bb+cc-dd)*0.5f;
            const float hh = (a-bb-cc+dd)*0.5f;
            const int i1 = (p<<1)+di, j1 = (q<<1)+dj;
            const size_t bb0 = (((size_t)b*3*64 + i1)*64 + j1)*C_ + c;
            bands[bb0]             = lh;
            bands[bb0 +   bstride] = hl;
            bands[bb0 + 2*bstride] = hh;
        }
    const float a = ll[0][0], bb = ll[0][1], cc = ll[1][0], dd = ll[1][1];
    const float l2  = (a+bb+cc+dd)*0.5f;
    const float lh2 = (a+bb-cc-dd)*0.5f;
    const float hl2 = (a-bb+cc-dd)*0.5f;
    const float hh2 = (a-bb-cc+dd)*0.5f;
    const size_t ub = (size_t)b*LS_*C_ + c;
    u[ub + (size_t)((p<<6)+q)*C_]          = l2;   // Yl2  -> s = p*64+q
    u[ub + (size_t)((p<<6)+32+q)*C_]       = lh2;  // lh2  -> cols 32..63
    u[ub + (size_t)(((32+p)<<6)+q)*C_]     = hl2;  // hl2  -> rows 32..63
    u[ub + (size_t)(((32+p)<<6)+32+q)*C_]  = hh2;
}

// ============================================================================
// Prep: per active position s: x_dbl = u @ x_proj_w^T (24), delta = softplus(
// dts @ dt_proj_w^T + b), Bs, Cs (= x_dbl part + prompt). 64 positions/block.
// ============================================================================
__global__ __launch_bounds__(256) void k_prep(const float* __restrict__ u,
        const float* __restrict__ prompt, const float* __restrict__ xw,
        const float* __restrict__ dtw, const float* __restrict__ dtb,
        float* __restrict__ delta, float* __restrict__ Bsv, float* __restrict__ Csv) {
    __shared__ float us[64*133];    // us[pos*133 + k]
    __shared__ float xws[128*26];   // xws[k*26 + r]
    __shared__ float xdbl[64*26];   // xdbl[pos*26 + r]
    const int tid = threadIdx.x;
    const int b = blockIdx.x >> 6;
    const int s0 = (blockIdx.x & 63) << 6;
    { // stage u tile
        const int pp = tid >> 5, k4 = (tid & 31) << 2;
        #pragma unroll
        for (int i = 0; i < 8; ++i) {
            const int pos = pp + (i << 3);
            const float4 v = *(const float4*)(u + ((size_t)b*LS_ + s0 + pos)*C_ + k4);
            us[pos*133 + k4 + 0] = v.x;
            us[pos*133 + k4 + 1] = v.y;
            us[pos*133 + k4 + 2] = v.z;
            us[pos*133 + k4 + 3] = v.w;
        }
    }
    for (int idx = tid; idx < 128*24; idx += 256) {
        const int k = idx / 24, r = idx - k*24;
        xws[k*26 + r] = xw[r*C_ + k];
    }
    __syncthreads();
    { // phase 1: x_dbl
        const int pos = tid & 63, ty = tid >> 6;   // ty in 0..3, 6 r's each
        float acc[6] = {0.f,0.f,0.f,0.f,0.f,0.f};
        for (int k = 0; k < 128; ++k) {
            const float a = us[pos*133 + k];
            #pragma unroll
            for (int rr = 0; rr < 6; ++rr)
                acc[rr] += a * xws[k*26 + ty*6 + rr];
        }
        #pragma unroll
        for (int rr = 0; rr < 6; ++rr) xdbl[pos*26 + ty*6 + rr] = acc[rr];
    }
    __syncthreads();
    { // phase 2: delta
        const int c = tid & 127, ph = tid >> 7;
        float wreg[8];
        *(float4*)&wreg[0] = *(const float4*)(dtw + c*8);
        *(float4*)&wreg[4] = *(const float4*)(dtw + c*8 + 4);
        const float bb = dtb[c];
        for (int i = 0; i < 32; ++i) {
            const int pos = ph*32 + i;
            float dd = bb;
            #pragma unroll
            for (int r = 0; r < 8; ++r) dd += xdbl[pos*26 + r] * wreg[r];
            delta[((size_t)b*LS_ + s0 + pos)*C_ + c] = softplus_f(dd);
        }
    }
    // phase 3: Bs / Cs (with prompt gathered at the true sequence index)
    #pragma unroll
    for (int i = 0; i < 2; ++i) {
        const int idx = (i << 8) + tid;       // 0..511
        const int pos = idx >> 3, n = idx & 7;
        const int s = s0 + pos;
        const int l = ((s >> 6) << 7) | (s & 63);
        Bsv[((size_t)b*LS_ + s)*N_ + n] = xdbl[pos*26 + 8 + n];
        Csv[((size_t)b*LS_ + s)*N_ + n] = xdbl[pos*26 + 16 + n]
                                        + prompt[((size_t)b*L_ + l)*N_ + n];
    }
}

// ============================================================================
// Scan pass 1: per (b,c,chunk) summary — composite transition exp(A*sum(delta))
// and end-state from h=0. threads: c = tid&127 (coalesced), 2 chunks/block.
// ============================================================================
__global__ __launch_bounds__(256) void k_scan1(const float* __restrict__ delta,
        const float* __restrict__ u, const float* __restrict__ Bsv,
        const float* __restrict__ Alog, float* __restrict__ dsum, float* __restrict__ hend) {
    const int tid = threadIdx.x;
    const int b = blockIdx.x >> 7, k2 = blockIdx.x & 127;
    const int k = (k2 << 1) | (tid >> 7);
    const int c = tid & 127;
    float al[8];
    *(float4*)&al[0] = *(const float4*)(Alog + c*8);
    *(float4*)&al[4] = *(const float4*)(Alog + c*8 + 4);
    float an[8];
    #pragma unroll
    for (int n = 0; n < 8; ++n) an[n] = -__expf(al[n]);
    float h[8] = {0,0,0,0,0,0,0,0};
    float cum = 0.f;
    const int s0 = k << 4;
    for (int t = 0; t < CS_; ++t) {
        const int s = s0 + t;
        const size_t base = ((size_t)b*LS_ + s)*C_ + c;
        const float d  = delta[base];
        const float uu = u[base];
        float bv[8];
        const float4* bp = (const float4*)(Bsv + ((size_t)b*LS_ + s)*N_);
        *(float4*)&bv[0] = bp[0];
        *(float4*)&bv[4] = bp[1];
        cum += d;
        const float du = d * uu;
        #pragma unroll
        for (int n = 0; n < 8; ++n)
            h[n] = __expf(d*an[n])*h[n] + bv[n]*du;
    }
    const size_t idx = (size_t)(b*NC_ + k)*C_ + c;
    dsum[idx] = cum;
    *(float4*)(hend + idx*N_)     = make_float4(h[0],h[1],h[2],h[3]);
    *(float4*)(hend + idx*N_ + 4) = make_float4(h[4],h[5],h[6],h[7]);
}

// ============================================================================
// Scan pass 2: serial combine across 256 chunk boundaries per (b,c,n).
// Inter-row gaps (64 zero-input steps) fold to one constant decay factor
// exp(A * 64 * softplus(dt_proj_b)) applied at every 4th chunk boundary.
// ============================================================================
__global__ __launch_bounds__(256) void k_comb(const float* __restrict__ dsum,
        const float* __restrict__ hend, const float* __restrict__ Alog,
        const float* __restrict__ dtb, float* __restrict__ hin) {
    const int g = blockIdx.x * 256 + threadIdx.x;   // 0..4095
    const int b = g >> 10;
    const int c = (g >> 3) & 127;
    const int n = g & 7;
    const float a  = -__expf(Alog[c*N_ + n]);
    const float d0 = softplus_f(dtb[c]);
    const float dz = __expf(a * (64.f * d0));
    float carry = 0.f;
    for (int k = 0; k < NC_; ++k) {
        if (k && !(k & 3)) carry *= dz;    // crossed a spatial-row boundary
        const size_t idx = (size_t)(b*NC_ + k)*C_ + c;
        hin[idx*N_ + n] = carry;
        carry = __expf(a * dsum[idx]) * carry + hend[idx*N_ + n];
    }
}

// ============================================================================
// Scan pass 3: re-run each chunk from its true h_in, emit y (+ u*D) -> h11
// ============================================================================
__global__ __launch_bounds__(256) void k_scan2(const float* __restrict__ delta,
        const float* __restrict__ u, const float* __restrict__ Bsv,
        const float* __restrict__ Csv, const float* __restrict__ Alog,
        const float* __restrict__ Ds, const float* __restrict__ hin,
        float* __restrict__ h11) {
    const int tid = threadIdx.x;
    const int b = blockIdx.x >> 7, k2 = blockIdx.x & 127;
    const int k = (k2 << 1) | (tid >> 7);
    const int c = tid & 127;
    float al[8];
    *(float4*)&al[0] = *(const float4*)(Alog + c*8);
    *(float4*)&al[4] = *(const float4*)(Alog + c*8 + 4);
    float an[8];
    #pragma unroll
    for (int n = 0; n < 8; ++n) an[n] = -__expf(al[n]);
    float h[8];
    const float4* hp = (const float4*)(hin + ((size_t)(b*NC_ + k)*C_ + c)*N_);
    *(float4*)&h[0] = hp[0];
    *(float4*)&h[4] = hp[1];
    const float dsc = Ds[c];
    const int s0 = k << 4;
    for (int t = 0; t < CS_; ++t) {
        const int s = s0 + t;
        const size_t base = ((size_t)b*LS_ + s)*C_ + c;
        const float d  = delta[base];
        const float uu = u[base];
        float bv[8], cv[8];
        const float4* bp = (const float4*)(Bsv + ((size_t)b*LS_ + s)*N_);
        const float4* cp = (const float4*)(Csv + ((size_t)b*LS_ + s)*N_);
        *(float4*)&bv[0] = bp[0];
        *(float4*)&bv[4] = bp[1];
        *(float4*)&cv[0] = cp[0];
        *(float4*)&cv[4] = cp[1];
        const float du = d * uu;
        float y = uu * dsc;
        #pragma unroll
        for (int n = 0; n < 8; ++n) {
            h[n] = __expf(d*an[n])*h[n] + bv[n]*du;
            y += h[n] * cv[n];
        }
        h11[base] = y;
    }
}

// ============================================================================
// 2-level inverse Haar DWT: h11 (active region) + bands1 -> recons (B,L,C)
// ============================================================================
__global__ __launch_bounds__(128) void k_idwt(const float* __restrict__ h11,
        const float* __restrict__ bands, float* __restrict__ rec) {
    const int c = threadIdx.x;
    const int bid = blockIdx.x;
    const int b = bid >> 10, p = (bid >> 5) & 31, q = bid & 31;
    const size_t ub = (size_t)b*LS_*C_ + c;
    const float l2  = h11[ub + (size_t)((p<<6)+q)*C_];
    const float lh2 = h11[ub + (size_t)((p<<6)+32+q)*C_];
    const float hl2 = h11[ub + (size_t)(((32+p)<<6)+q)*C_];
    const float hh2 = h11[ub + (size_t)(((32+p)<<6)+32+q)*C_];
    float yl1[2][2];
    yl1[0][0] = (l2+lh2+hl2+hh2)*0.5f;
    yl1[0][1] = (l2+lh2-hl2-hh2)*0.5f;
    yl1[1][0] = (l2-lh2+hl2-hh2)*0.5f;
    yl1[1][1] = (l2-lh2-hl2+hh2)*0.5f;
    const size_t bstride = (size_t)64*64*C_;
    #pragma unroll
    for (int di = 0; di < 2; ++di)
        #pragma unroll
        for (int dj = 0; dj < 2; ++dj) {
            const int i1 = (p<<1)+di, j1 = (q<<1)+dj;
            const size_t bb0 = (((size_t)b*3*64 + i1)*64 + j1)*C_ + c;
            const float lh = bands[bb0];
            const float hl = bands[bb0 +   bstride];
            const float hh = bands[bb0 + 2*bstride];
            const float ll = yl1[di][dj];
            const float a  = (ll+lh+hl+hh)*0.5f;
            const float bo = (ll+lh-hl-hh)*0.5f;
            const float co = (ll-lh+hl-hh)*0.5f;
            const float d2 = (ll-lh-hl+hh)*0.5f;
            const int hh_ = i1 << 1, ww_ = j1 << 1;
            const size_t rb = ((size_t)b*L_ + (size_t)hh_*W_ + ww_)*C_ + c;
            rec[rb]                      = a;
            rec[rb + C_]                 = bo;
            rec[rb + (size_t)W_*C_]      = co;
            rec[rb + (size_t)W_*C_ + C_] = d2;
        }
}

// ============================================================================
// LayerNorm over C + SiLU(z) gate, in-place on recons. One wave per row.
// ============================================================================
__global__ __launch_bounds__(256) void k_ln(float* __restrict__ yr,
        const float* __restrict__ z, const float* __restrict__ gamma,
        const float* __restrict__ beta) {
    const int lane = threadIdx.x & 63;
    const size_t row = ((size_t)blockIdx.x << 2) + (threadIdx.x >> 6);
    const size_t base = row * C_;
    const float v0 = yr[base + lane], v1 = yr[base + 64 + lane];
    float s = v0 + v1, ss = v0*v0 + v1*v1;
    #pragma unroll
    for (int off = 1; off < 64; off <<= 1) {
        s  += __shfl_xor(s,  off);
        ss += __shfl_xor(ss, off);
    }
    const float mu  = s * 0.0078125f;
    const float var = ss * 0.0078125f - mu*mu;
    const float ri  = rsqrtf(var + 1e-5f);
    float y0 = (v0 - mu)*ri*gamma[lane]      + beta[lane];
    float y1 = (v1 - mu)*ri*gamma[lane + 64] + beta[lane + 64];
    const float z0 = z[base + lane], z1 = z[base + 64 + lane];
    y0 *= z0 / (1.f + __expf(-z0));
    y1 *= z1 / (1.f + __expf(-z1));
    yr[base + lane]      = y0;
    yr[base + 64 + lane] = y1;
}

// ============================================================================
extern "C" void kernel_launch(void* const* d_in, const int* in_sizes, int n_in,
                              void* d_out, int out_size, void* d_ws, size_t ws_size,
                              hipStream_t stream) {
    (void)in_sizes; (void)n_in; (void)out_size; (void)ws_size;
    const float* x      = (const float*)d_in[0];
    const float* prompt = (const float*)d_in[1];
    const float* in_w   = (const float*)d_in[2];
    const float* x_w    = (const float*)d_in[3];
    const float* dt_w   = (const float*)d_in[4];
    const float* dt_b   = (const float*)d_in[5];
    const float* A_logs = (const float*)d_in[6];
    const float* Ds     = (const float*)d_in[7];
    const float* gam    = (const float*)d_in[8];
    const float* bet    = (const float*)d_in[9];
    const float* out_w  = (const float*)d_in[10];
    const float* out_b  = (const float*)d_in[11];
    float* wsp   = (float*)d_ws;
    float* xproc = wsp + OFF_XPROC;   // later reused for recons / gated y
    float* z     = wsp + OFF_Z;
    float* bands = wsp + OFF_BANDS;
    float* u     = wsp + OFF_U;
    float* delta = wsp + OFF_DELTA;
    float* Bs    = wsp + OFF_BS;
    float* Cs    = wsp + OFF_CS;
    float* dsum  = wsp + OFF_DSUM;
    float* hend  = wsp + OFF_HEND;
    float* hin   = wsp + OFF_HIN;
    float* h11   = wsp + OFF_H11;
    float* out   = (float*)d_out;

    // 1) in_proj GEMM -> x_proc, z
    k_gemm<4,false><<<512, 256, 0, stream>>>(x, in_w, xproc, z, nullptr, nullptr);
    // 2) 2-level DWT -> bands1 + compact active-region u
    k_dwt<<<4096, 128, 0, stream>>>(xproc, bands, u);
    // 3) x_proj / dt_proj / prompt -> delta, Bs, Cs
    k_prep<<<256, 256, 0, stream>>>(u, prompt, x_w, dt_w, dt_b, delta, Bs, Cs);
    // 4) chunked scan: summaries
    k_scan1<<<512, 256, 0, stream>>>(delta, u, Bs, A_logs, dsum, hend);
    // 5) serial combine across chunk boundaries (with inter-row decay)
    k_comb<<<16, 256, 0, stream>>>(dsum, hend, A_logs, dt_b, hin);
    // 6) re-scan with true initial states -> h11 (scan output + u*D)
    k_scan2<<<512, 256, 0, stream>>>(delta, u, Bs, Cs, A_logs, Ds, hin, h11);
    // 7) 2-level inverse DWT -> recons (into xproc buffer)
    k_idwt<<<4096, 128, 0, stream>>>(h11, bands, xproc);
    // 8) LayerNorm + SiLU(z) gate, in-place
    k_ln<<<16384, 256, 0, stream>>>(xproc, z, gam, bet);
    // 9) out_proj GEMM + bias + residual -> d_out
    k_gemm<2,true><<<512, 256, 0, stream>>>(xproc, out_w, out, nullptr, out_b, x);
}

// Round 2
// 260.862 us; speedup vs baseline: 1.3332x; 1.3332x over previous
//
#include <hip/hip_runtime.h>

// Problem constants (fixed by setup_inputs)
#define B_   4
#define H_   128
#define W_   128
#define L_   (H_*W_)        // 16384
#define C_   128
#define N_   8
#define R_   8
#define LS_  4096           // active scan positions per batch (64x64 top-left region)
#define CS_  16             // scan chunk length (steps)
#define NC_  256            // chunks per (b,c) = LS_/CS_

// ---- workspace layout (in floats) ----
#define OFF_XPROC 0ull
#define OFF_Z     (OFF_XPROC + (size_t)B_*L_*C_)
#define OFF_BANDS (OFF_Z     + (size_t)B_*L_*C_)                 // bands1: [B][3][64][64][C]
#define OFF_U     (OFF_BANDS + (size_t)B_*3*64*64*C_)            // u  [B][4096][C]
#define OFF_DELTA (OFF_U     + (size_t)B_*LS_*C_)
#define OFF_BS    (OFF_DELTA + (size_t)B_*LS_*C_)                // [B][4096][8]
#define OFF_CS    (OFF_BS    + (size_t)B_*LS_*N_)
#define OFF_DSUM  (OFF_CS    + (size_t)B_*LS_*N_)                // [B][NC][C]
#define OFF_HEND  (OFF_DSUM  + (size_t)B_*NC_*C_)                // [B][NC][C][8]
#define OFF_HIN   (OFF_HEND  + (size_t)B_*NC_*C_*N_)
#define OFF_H11   (OFF_HIN   + (size_t)B_*NC_*C_*N_)             // [B][4096][C]
#define OFF_WCVT  (OFF_H11   + (size_t)B_*LS_*C_)                // ushort region: split weights

typedef __attribute__((ext_vector_type(8))) short bf16x8;
typedef __attribute__((ext_vector_type(4))) float f32x4;

__device__ __forceinline__ float softplus_f(float x) {
    return (x > 20.f) ? x : log1pf(__expf(x));
}

// split fp32 into bf16 hi (round-nearest) + bf16 lo (truncated residual)
__device__ __forceinline__ void split_bf16(float x, short& h, short& l) {
    const unsigned u  = __float_as_uint(x);
    const unsigned hr = (u + 0x7FFFu + ((u >> 16) & 1u)) >> 16;
    h = (short)hr;
    const float hf = __uint_as_float(hr << 16);
    l = (short)(__float_as_uint(x - hf) >> 16);
}

__device__ __forceinline__ f32x4 mfma16(bf16x8 a, bf16x8 b, f32x4 c) {
    return __builtin_amdgcn_mfma_f32_16x16x32_bf16(a, b, c, 0, 0, 0);
}

// ============================================================================
// Weight split: in_proj_w (256x128) and out_proj_w (128x128) -> bf16 hi/lo
// ============================================================================
__global__ __launch_bounds__(256) void k_cvt(const float* __restrict__ w_in,
        const float* __restrict__ w_out, unsigned short* __restrict__ wq) {
    const int i = blockIdx.x * 256 + threadIdx.x;   // 0..49151
    float v; unsigned short *hi, *lo; int idx;
    if (i < 32768) { v = w_in[i];          hi = wq;         lo = wq + 32768; idx = i; }
    else           { v = w_out[i - 32768]; hi = wq + 65536; lo = wq + 81920; idx = i - 32768; }
    short h, l; split_bf16(v, h, l);
    hi[idx] = (unsigned short)h;
    lo[idx] = (unsigned short)l;
}

// ============================================================================
// MFMA split-bf16 GEMM: out[M x NJ] = in[M x 128] @ w[NJ x 128]^T
// Wave tile 32x64 (8 16x16 frags). !EPI: 4 waves side-by-side, NJ=256,
// cols 0-127 -> out0, 128-255 -> out1. EPI: 2x2 waves, NJ=128, +bias+resid.
// No LDS; B from pre-split global (L1/L2-hot), A converted in-register.
// ============================================================================
template<bool EPI>
__global__ __launch_bounds__(256) void k_gemm_mfma(const float* __restrict__ in,
        const unsigned short* __restrict__ whi, const unsigned short* __restrict__ wlo,
        float* __restrict__ out0, float* __restrict__ out1,
        const float* __restrict__ bias, const float* __restrict__ resid) {
    const int tid  = threadIdx.x;
    const int wave = tid >> 6, lane = tid & 63;
    const int lrow = lane & 15;
    const int lk8  = (lane >> 4) << 3;
    int r0, c0;
    if constexpr (EPI) { r0 = blockIdx.x * 64 + (wave >> 1) * 32; c0 = (wave & 1) * 64; }
    else               { r0 = blockIdx.x * 32;                    c0 = wave * 64; }

    f32x4 acc[2][4];
    #pragma unroll
    for (int rb = 0; rb < 2; ++rb)
        #pragma unroll
        for (int cb = 0; cb < 4; ++cb)
            acc[rb][cb] = (f32x4){0.f, 0.f, 0.f, 0.f};

    const float* a0 = in + (size_t)(r0 + lrow) * C_ + lk8;
    const float* a1 = in + (size_t)(r0 + 16 + lrow) * C_ + lk8;

    #pragma unroll
    for (int ks = 0; ks < 4; ++ks) {
        bf16x8 ah[2], al[2];
        #pragma unroll
        for (int rb = 0; rb < 2; ++rb) {
            const float* ap = (rb ? a1 : a0) + ks * 32;
            const float4 v0 = *(const float4*)ap;
            const float4 v1 = *(const float4*)(ap + 4);
            const float f[8] = {v0.x, v0.y, v0.z, v0.w, v1.x, v1.y, v1.z, v1.w};
            #pragma unroll
            for (int i = 0; i < 8; ++i) {
                short h, l; split_bf16(f[i], h, l);
                ah[rb][i] = h; al[rb][i] = l;
            }
        }
        #pragma unroll
        for (int cb = 0; cb < 4; ++cb) {
            const size_t boff = (size_t)(c0 + cb * 16 + lrow) * C_ + ks * 32 + lk8;
            const bf16x8 bh = *(const bf16x8*)(whi + boff);
            const bf16x8 bl = *(const bf16x8*)(wlo + boff);
            #pragma unroll
            for (int rb = 0; rb < 2; ++rb) {
                f32x4 t = acc[rb][cb];
                t = mfma16(ah[rb], bh, t);
                t = mfma16(ah[rb], bl, t);
                t = mfma16(al[rb], bh, t);
                acc[rb][cb] = t;
            }
        }
    }
    // epilogue: C/D layout col=lane&15, row=(lane>>4)*4+reg  [m89-verified]
    #pragma unroll
    for (int rb = 0; rb < 2; ++rb)
        #pragma unroll
        for (int cb = 0; cb < 4; ++cb) {
            const int col = c0 + cb * 16 + lrow;
            float* op; int colo;
            if constexpr (EPI) { op = out0; colo = col; }
            else { const bool toz = (c0 + cb * 16) >= 128; op = toz ? out1 : out0; colo = col & 127; }
            const float bz = EPI ? bias[colo] : 0.f;
            #pragma unroll
            for (int j = 0; j < 4; ++j) {
                const size_t row = (size_t)r0 + rb * 16 + (lane >> 4) * 4 + j;
                float v = acc[rb][cb][j] + bz;
                if constexpr (EPI) v += resid[row * C_ + colo];
                op[row * C_ + colo] = v;
            }
        }
}

// ============================================================================
// 2-level Haar DWT: x_proc (B,L,C) -> bands1 [B][3][64][64][C] + compact u
// ============================================================================
__global__ __launch_bounds__(128) void k_dwt(const float* __restrict__ xp,
        float* __restrict__ bands, float* __restrict__ u) {
    const int c = threadIdx.x;
    const int bid = blockIdx.x;
    const int b = bid >> 10, p = (bid >> 5) & 31, q = bid & 31;
    float v[4][4];
    const size_t base = (size_t)b * L_ * C_ + c;
    #pragma unroll
    for (int i = 0; i < 4; ++i)
        #pragma unroll
        for (int j = 0; j < 4; ++j)
            v[i][j] = xp[base + (size_t)(((p<<2)+i)*W_ + (q<<2)+j) * C_];
    const size_t bstride = (size_t)64*64*C_;
    float ll[2][2];
    #pragma unroll
    for (int di = 0; di < 2; ++di)
        #pragma unroll
        for (int dj = 0; dj < 2; ++dj) {
            const float a  = v[2*di][2*dj],   bb = v[2*di][2*dj+1];
            const float cc = v[2*di+1][2*dj], dd = v[2*di+1][2*dj+1];
            ll[di][dj]     = (a+bb+cc+dd)*0.5f;
            const float lh = (a+bb-cc-dd)*0.5f;
            const float hl = (a-bb+cc-dd)*0.5f;
            const float hh = (a-bb-cc+dd)*0.5f;
            const int i1 = (p<<1)+di, j1 = (q<<1)+dj;
            const size_t bb0 = (((size_t)b*3*64 + i1)*64 + j1)*C_ + c;
            bands[bb0]             = lh;
            bands[bb0 +   bstride] = hl;
            bands[bb0 + 2*bstride] = hh;
        }
    const float a = ll[0][0], bb = ll[0][1], cc = ll[1][0], dd = ll[1][1];
    const float l2  = (a+bb+cc+dd)*0.5f;
    const float lh2 = (a+bb-cc-dd)*0.5f;
    const float hl2 = (a-bb+cc-dd)*0.5f;
    const float hh2 = (a-bb-cc+dd)*0.5f;
    const size_t ub = (size_t)b*LS_*C_ + c;
    u[ub + (size_t)((p<<6)+q)*C_]          = l2;
    u[ub + (size_t)((p<<6)+32+q)*C_]       = lh2;
    u[ub + (size_t)(((32+p)<<6)+q)*C_]     = hl2;
    u[ub + (size_t)(((32+p)<<6)+32+q)*C_]  = hh2;
}

// ============================================================================
// Prep: x_dbl = u @ x_proj_w^T, delta = softplus(dts @ dt_proj_w^T + b), Bs, Cs
// ============================================================================
__global__ __launch_bounds__(256) void k_prep(const float* __restrict__ u,
        const float* __restrict__ prompt, const float* __restrict__ xw,
        const float* __restrict__ dtw, const float* __restrict__ dtb,
        float* __restrict__ delta, float* __restrict__ Bsv, float* __restrict__ Csv) {
    __shared__ float us[64*133];
    __shared__ float xws[128*26];
    __shared__ float xdbl[64*26];
    const int tid = threadIdx.x;
    const int b = blockIdx.x >> 6;
    const int s0 = (blockIdx.x & 63) << 6;
    {
        const int pp = tid >> 5, k4 = (tid & 31) << 2;
        #pragma unroll
        for (int i = 0; i < 8; ++i) {
            const int pos = pp + (i << 3);
            const float4 v = *(const float4*)(u + ((size_t)b*LS_ + s0 + pos)*C_ + k4);
            us[pos*133 + k4 + 0] = v.x;
            us[pos*133 + k4 + 1] = v.y;
            us[pos*133 + k4 + 2] = v.z;
            us[pos*133 + k4 + 3] = v.w;
        }
    }
    for (int idx = tid; idx < 128*24; idx += 256) {
        const int k = idx / 24, r = idx - k*24;
        xws[k*26 + r] = xw[r*C_ + k];
    }
    __syncthreads();
    {
        const int pos = tid & 63, ty = tid >> 6;
        float acc[6] = {0.f,0.f,0.f,0.f,0.f,0.f};
        for (int k = 0; k < 128; ++k) {
            const float a = us[pos*133 + k];
            #pragma unroll
            for (int rr = 0; rr < 6; ++rr)
                acc[rr] += a * xws[k*26 + ty*6 + rr];
        }
        #pragma unroll
        for (int rr = 0; rr < 6; ++rr) xdbl[pos*26 + ty*6 + rr] = acc[rr];
    }
    __syncthreads();
    {
        const int c = tid & 127, ph = tid >> 7;
        float wreg[8];
        *(float4*)&wreg[0] = *(const float4*)(dtw + c*8);
        *(float4*)&wreg[4] = *(const float4*)(dtw + c*8 + 4);
        const float bb = dtb[c];
        for (int i = 0; i < 32; ++i) {
            const int pos = ph*32 + i;
            float dd = bb;
            #pragma unroll
            for (int r = 0; r < 8; ++r) dd += xdbl[pos*26 + r] * wreg[r];
            delta[((size_t)b*LS_ + s0 + pos)*C_ + c] = softplus_f(dd);
        }
    }
    #pragma unroll
    for (int i = 0; i < 2; ++i) {
        const int idx = (i << 8) + tid;
        const int pos = idx >> 3, n = idx & 7;
        const int s = s0 + pos;
        const int l = ((s >> 6) << 7) | (s & 63);
        Bsv[((size_t)b*LS_ + s)*N_ + n] = xdbl[pos*26 + 8 + n];
        Csv[((size_t)b*LS_ + s)*N_ + n] = xdbl[pos*26 + 16 + n]
                                        + prompt[((size_t)b*L_ + l)*N_ + n];
    }
}

// ============================================================================
// Scan pass 1: per (b,c,chunk) summary
// ============================================================================
__global__ __launch_bounds__(256) void k_scan1(const float* __restrict__ delta,
        const float* __restrict__ u, const float* __restrict__ Bsv,
        const float* __restrict__ Alog, float* __restrict__ dsum, float* __restrict__ hend) {
    const int tid = threadIdx.x;
    const int b = blockIdx.x >> 7, k2 = blockIdx.x & 127;
    const int k = (k2 << 1) | (tid >> 7);
    const int c = tid & 127;
    float al[8];
    *(float4*)&al[0] = *(const float4*)(Alog + c*8);
    *(float4*)&al[4] = *(const float4*)(Alog + c*8 + 4);
    float an[8];
    #pragma unroll
    for (int n = 0; n < 8; ++n) an[n] = -__expf(al[n]);
    float h[8] = {0,0,0,0,0,0,0,0};
    float cum = 0.f;
    const int s0 = k << 4;
    for (int t = 0; t < CS_; ++t) {
        const int s = s0 + t;
        const size_t base = ((size_t)b*LS_ + s)*C_ + c;
        const float d  = delta[base];
        const float uu = u[base];
        float bv[8];
        const float4* bp = (const float4*)(Bsv + ((size_t)b*LS_ + s)*N_);
        *(float4*)&bv[0] = bp[0];
        *(float4*)&bv[4] = bp[1];
        cum += d;
        const float du = d * uu;
        #pragma unroll
        for (int n = 0; n < 8; ++n)
            h[n] = __expf(d*an[n])*h[n] + bv[n]*du;
    }
    const size_t idx = (size_t)(b*NC_ + k)*C_ + c;
    dsum[idx] = cum;
    *(float4*)(hend + idx*N_)     = make_float4(h[0],h[1],h[2],h[3]);
    *(float4*)(hend + idx*N_ + 4) = make_float4(h[4],h[5],h[6],h[7]);
}

// ============================================================================
// Scan pass 2: serial combine, double-buffered batch-16 prefetch
// ============================================================================
#define KB_ 16
__global__ __launch_bounds__(256) void k_comb(const float* __restrict__ dsum,
        const float* __restrict__ hend, const float* __restrict__ Alog,
        const float* __restrict__ dtb, float* __restrict__ hin) {
    const int g = blockIdx.x * 256 + threadIdx.x;   // 0..4095
    const int b = g >> 10;
    const int c = (g >> 3) & 127;
    const int n = g & 7;
    const float a  = -__expf(Alog[c*N_ + n]);
    const float d0 = softplus_f(dtb[c]);
    const float dz = __expf(a * (64.f * d0));
    float carry = 0.f;
    float ea[KB_], ha[KB_], eb[KB_], hb[KB_];
    auto LOAD = [&](int kb, float* e, float* hv) {
        #pragma unroll
        for (int j = 0; j < KB_; ++j) {
            const size_t idx = (size_t)(b*NC_ + kb + j)*C_ + c;
            e[j]  = a * dsum[idx];
            hv[j] = hend[idx*N_ + n];
        }
    };
    auto CHAIN = [&](int kb, const float* e, const float* hv) {
        #pragma unroll
        for (int j = 0; j < KB_; ++j) {
            const int k = kb + j;
            if (k && !(k & 3)) carry *= dz;
            hin[((size_t)(b*NC_ + k)*C_ + c)*N_ + n] = carry;
            carry = __expf(e[j])*carry + hv[j];
        }
    };
    LOAD(0, ea, ha);
    for (int kb = 0; kb < NC_; kb += 2*KB_) {
        LOAD(kb + KB_, eb, hb);
        CHAIN(kb, ea, ha);
        if (kb + 2*KB_ < NC_) LOAD(kb + 2*KB_, ea, ha);
        CHAIN(kb + KB_, eb, hb);
    }
}

// ============================================================================
// Scan pass 3: re-run each chunk from true h_in -> h11
// ============================================================================
__global__ __launch_bounds__(256) void k_scan2(const float* __restrict__ delta,
        const float* __restrict__ u, const float* __restrict__ Bsv,
        const float* __restrict__ Csv, const float* __restrict__ Alog,
        const float* __restrict__ Ds, const float* __restrict__ hin,
        float* __restrict__ h11) {
    const int tid = threadIdx.x;
    const int b = blockIdx.x >> 7, k2 = blockIdx.x & 127;
    const int k = (k2 << 1) | (tid >> 7);
    const int c = tid & 127;
    float al[8];
    *(float4*)&al[0] = *(const float4*)(Alog + c*8);
    *(float4*)&al[4] = *(const float4*)(Alog + c*8 + 4);
    float an[8];
    #pragma unroll
    for (int n = 0; n < 8; ++n) an[n] = -__expf(al[n]);
    float h[8];
    const float4* hp = (const float4*)(hin + ((size_t)(b*NC_ + k)*C_ + c)*N_);
    *(float4*)&h[0] = hp[0];
    *(float4*)&h[4] = hp[1];
    const float dsc = Ds[c];
    const int s0 = k << 4;
    for (int t = 0; t < CS_; ++t) {
        const int s = s0 + t;
        const size_t base = ((size_t)b*LS_ + s)*C_ + c;
        const float d  = delta[base];
        const float uu = u[base];
        float bv[8], cv[8];
        const float4* bp = (const float4*)(Bsv + ((size_t)b*LS_ + s)*N_);
        const float4* cp = (const float4*)(Csv + ((size_t)b*LS_ + s)*N_);
        *(float4*)&bv[0] = bp[0];
        *(float4*)&bv[4] = bp[1];
        *(float4*)&cv[0] = cp[0];
        *(float4*)&cv[4] = cp[1];
        const float du = d * uu;
        float y = uu * dsc;
        #pragma unroll
        for (int n = 0; n < 8; ++n) {
            h[n] = __expf(d*an[n])*h[n] + bv[n]*du;
            y += h[n] * cv[n];
        }
        h11[base] = y;
    }
}

// ============================================================================
// Fused 2-level inverse Haar DWT + LayerNorm + SiLU gate -> y
// Block = 128 threads (channels); 16 output pixels per block.
// ============================================================================
__global__ __launch_bounds__(128) void k_idwt_ln(const float* __restrict__ h11,
        const float* __restrict__ bands, const float* __restrict__ z,
        const float* __restrict__ gamma, const float* __restrict__ beta,
        float* __restrict__ yout) {
    __shared__ float vb[16][129];
    __shared__ float stat[16][2];
    const int c = threadIdx.x;
    const int bid = blockIdx.x;
    const int b = bid >> 10, p = (bid >> 5) & 31, q = bid & 31;
    const size_t ub = (size_t)b*LS_*C_ + c;
    const float l2  = h11[ub + (size_t)((p<<6)+q)*C_];
    const float lh2 = h11[ub + (size_t)((p<<6)+32+q)*C_];
    const float hl2 = h11[ub + (size_t)(((32+p)<<6)+q)*C_];
    const float hh2 = h11[ub + (size_t)(((32+p)<<6)+32+q)*C_];
    float yl1[2][2];
    yl1[0][0] = (l2+lh2+hl2+hh2)*0.5f;
    yl1[0][1] = (l2+lh2-hl2-hh2)*0.5f;
    yl1[1][0] = (l2-lh2+hl2-hh2)*0.5f;
    yl1[1][1] = (l2-lh2-hl2+hh2)*0.5f;
    const size_t bstride = (size_t)64*64*C_;
    float v[16];
    #pragma unroll
    for (int di = 0; di < 2; ++di)
        #pragma unroll
        for (int dj = 0; dj < 2; ++dj) {
            const int i1 = (p<<1)+di, j1 = (q<<1)+dj;
            const size_t bb0 = (((size_t)b*3*64 + i1)*64 + j1)*C_ + c;
            const float lh = bands[bb0];
            const float hl = bands[bb0 +   bstride];
            const float hh = bands[bb0 + 2*bstride];
            const float ll = yl1[di][dj];
            v[(2*di+0)*4 + 2*dj+0] = (ll+lh+hl+hh)*0.5f;
            v[(2*di+0)*4 + 2*dj+1] = (ll+lh-hl-hh)*0.5f;
            v[(2*di+1)*4 + 2*dj+0] = (ll-lh+hl-hh)*0.5f;
            v[(2*di+1)*4 + 2*dj+1] = (ll-lh-hl+hh)*0.5f;
        }
    #pragma unroll
    for (int p16 = 0; p16 < 16; ++p16) vb[p16][c] = v[p16];
    __syncthreads();
    {   // each 8-lane group reduces one pixel over C=128
        const int pp = c >> 3, gg = c & 7;
        float s = 0.f, ss = 0.f;
        #pragma unroll
        for (int i = 0; i < 16; ++i) {
            const float x = vb[pp][gg*16 + i];
            s += x; ss += x*x;
        }
        s += __shfl_xor(s, 1); ss += __shfl_xor(ss, 1);
        s += __shfl_xor(s, 2); ss += __shfl_xor(ss, 2);
        s += __shfl_xor(s, 4); ss += __shfl_xor(ss, 4);
        if (gg == 0) { stat[pp][0] = s; stat[pp][1] = ss; }
    }
    __syncthreads();
    const float gm = gamma[c], bt = beta[c];
    #pragma unroll
    for (int p16 = 0; p16 < 16; ++p16) {
        const int lr = p16 >> 2, lc = p16 & 3;
        const size_t l = (size_t)((p<<2)+lr)*W_ + (q<<2)+lc;
        const float mu  = stat[p16][0] * 0.0078125f;
        const float var = stat[p16][1] * 0.0078125f - mu*mu;
        const float ri  = rsqrtf(var + 1e-5f);
        float y = (v[p16] - mu)*ri*gm + bt;
        const float zv = z[((size_t)b*L_ + l)*C_ + c];
        y *= zv / (1.f + __expf(-zv));
        yout[((size_t)b*L_ + l)*C_ + c] = y;
    }
}

// ============================================================================
extern "C" void kernel_launch(void* const* d_in, const int* in_sizes, int n_in,
                              void* d_out, int out_size, void* d_ws, size_t ws_size,
                              hipStream_t stream) {
    (void)in_sizes; (void)n_in; (void)out_size; (void)ws_size;
    const float* x      = (const float*)d_in[0];
    const float* prompt = (const float*)d_in[1];
    const float* in_w   = (const float*)d_in[2];
    const float* x_w    = (const float*)d_in[3];
    const float* dt_w   = (const float*)d_in[4];
    const float* dt_b   = (const float*)d_in[5];
    const float* A_logs = (const float*)d_in[6];
    const float* Ds     = (const float*)d_in[7];
    const float* gam    = (const float*)d_in[8];
    const float* bet    = (const float*)d_in[9];
    const float* out_w  = (const float*)d_in[10];
    const float* out_b  = (const float*)d_in[11];
    float* wsp   = (float*)d_ws;
    float* xproc = wsp + OFF_XPROC;   // later reused for gated y
    float* z     = wsp + OFF_Z;
    float* bands = wsp + OFF_BANDS;
    float* u     = wsp + OFF_U;
    float* delta = wsp + OFF_DELTA;
    float* Bs    = wsp + OFF_BS;
    float* Cs    = wsp + OFF_CS;
    float* dsum  = wsp + OFF_DSUM;
    float* hend  = wsp + OFF_HEND;
    float* hin   = wsp + OFF_HIN;
    float* h11   = wsp + OFF_H11;
    unsigned short* wq = (unsigned short*)(wsp + OFF_WCVT);
    unsigned short* whi_in  = wq;
    unsigned short* wlo_in  = wq + 32768;
    unsigned short* whi_out = wq + 65536;
    unsigned short* wlo_out = wq + 81920;
    float* out   = (float*)d_out;

    // 0) split weights into bf16 hi/lo
    k_cvt<<<192, 256, 0, stream>>>(in_w, out_w, wq);
    // 1) in_proj GEMM (MFMA split-bf16) -> x_proc, z
    k_gemm_mfma<false><<<2048, 256, 0, stream>>>(x, whi_in, wlo_in, xproc, z, nullptr, nullptr);
    // 2) 2-level DWT -> bands1 + compact active-region u
    k_dwt<<<4096, 128, 0, stream>>>(xproc, bands, u);
    // 3) x_proj / dt_proj / prompt -> delta, Bs, Cs
    k_prep<<<256, 256, 0, stream>>>(u, x_w ? prompt : prompt, x_w, dt_w, dt_b, delta, Bs, Cs);
    // 4) chunked scan: summaries
    k_scan1<<<512, 256, 0, stream>>>(delta, u, Bs, A_logs, dsum, hend);
    // 5) serial combine across chunk boundaries
    k_comb<<<16, 256, 0, stream>>>(dsum, hend, A_logs, dt_b, hin);
    // 6) re-scan with true initial states -> h11
    k_scan2<<<512, 256, 0, stream>>>(delta, u, Bs, Cs, A_logs, Ds, hin, h11);
    // 7) fused inverse DWT + LayerNorm + SiLU gate -> y (xproc buffer)
    k_idwt_ln<<<4096, 128, 0, stream>>>(h11, bands, z, gam, bet, xproc);
    // 8) out_proj GEMM + bias + residual -> d_out
    k_gemm_mfma<true><<<1024, 256, 0, stream>>>(xproc, whi_out, wlo_out, out, nullptr, out_b, x);
}

// Round 3
// 257.988 us; speedup vs baseline: 1.3481x; 1.0111x over previous
//
#include <hip/hip_runtime.h>

// Problem constants (fixed by setup_inputs)
#define B_   4
#define H_   128
#define W_   128
#define L_   (H_*W_)        // 16384
#define C_   128
#define N_   8
#define R_   8
#define LS_  4096           // active scan positions per batch (64x64 top-left region)
#define CS_  16             // scan chunk length (steps)
#define NC_  256            // chunks per (b,c) = LS_/CS_
#define ST_  (B_*LS_)       // 16384 total active rows

// ---- workspace layout (in floats) ----
#define OFF_XPROC 0ull
#define OFF_Z     (OFF_XPROC + (size_t)B_*L_*C_)
#define OFF_BANDS (OFF_Z     + (size_t)B_*L_*C_)                 // bands1: [B][3][64][64][C]
#define OFF_U     (OFF_BANDS + (size_t)B_*3*64*64*C_)            // u  [B][4096][C]
#define OFF_DELTA (OFF_U     + (size_t)B_*LS_*C_)
#define OFF_BS    (OFF_DELTA + (size_t)B_*LS_*C_)                // [B][4096][8]
#define OFF_CS    (OFF_BS    + (size_t)B_*LS_*N_)
#define OFF_DSUM  (OFF_CS    + (size_t)B_*LS_*N_)                // [B][NC][C]
#define OFF_HEND  (OFF_DSUM  + (size_t)B_*NC_*C_)                // [B][NC][C][8]
#define OFF_HIN   (OFF_HEND  + (size_t)B_*NC_*C_*N_)
#define OFF_H11   (OFF_HIN   + (size_t)B_*NC_*C_*N_)             // [B][4096][C]
#define OFF_XDBL  (OFF_H11   + (size_t)B_*LS_*C_)                // [ST][32] fp32
#define OFF_WCVT  (OFF_XDBL  + (size_t)ST_*32)                   // ushort region: split weights

typedef __attribute__((ext_vector_type(8))) short bf16x8;
typedef __attribute__((ext_vector_type(4))) float f32x4;

__device__ __forceinline__ float softplus_f(float x) {
    return (x > 20.f) ? x : log1pf(__expf(x));
}

// split fp32 into bf16 hi (round-nearest) + bf16 lo (truncated residual)
__device__ __forceinline__ void split_bf16(float x, short& h, short& l) {
    const unsigned u  = __float_as_uint(x);
    const unsigned hr = (u + 0x7FFFu + ((u >> 16) & 1u)) >> 16;
    h = (short)hr;
    const float hf = __uint_as_float(hr << 16);
    l = (short)(__float_as_uint(x - hf) >> 16);
}

__device__ __forceinline__ f32x4 mfma16(bf16x8 a, bf16x8 b, f32x4 c) {
    return __builtin_amdgcn_mfma_f32_16x16x32_bf16(a, b, c, 0, 0, 0);
}

// ============================================================================
// Weight split: in_proj (256x128), out_proj (128x128), x_proj (24x128 pad 32)
// ============================================================================
__global__ __launch_bounds__(256) void k_cvt(const float* __restrict__ w_in,
        const float* __restrict__ w_out, const float* __restrict__ xw,
        unsigned short* __restrict__ wq) {
    const int i = blockIdx.x * 256 + threadIdx.x;   // 0..53247
    float v; unsigned short *hi, *lo; int idx;
    if (i < 32768)      { v = w_in[i];          hi = wq;         lo = wq + 32768;  idx = i; }
    else if (i < 49152) { v = w_out[i - 32768]; hi = wq + 65536; lo = wq + 81920;  idx = i - 32768; }
    else {
        idx = i - 49152;                         // 0..4095 over [32][128]
        v = (idx < 24*128) ? xw[idx] : 0.f;      // zero-pad rows 24..31
        hi = wq + 98304; lo = wq + 102400;
    }
    short h, l; split_bf16(v, h, l);
    hi[idx] = (unsigned short)h;
    lo[idx] = (unsigned short)l;
}

// ============================================================================
// MFMA split-bf16 GEMM: out[M x NJ] = in[M x 128] @ w[NJ x 128]^T
// ============================================================================
template<bool EPI>
__global__ __launch_bounds__(256) void k_gemm_mfma(const float* __restrict__ in,
        const unsigned short* __restrict__ whi, const unsigned short* __restrict__ wlo,
        float* __restrict__ out0, float* __restrict__ out1,
        const float* __restrict__ bias, const float* __restrict__ resid) {
    const int tid  = threadIdx.x;
    const int wave = tid >> 6, lane = tid & 63;
    const int lrow = lane & 15;
    const int lk8  = (lane >> 4) << 3;
    int r0, c0;
    if constexpr (EPI) { r0 = blockIdx.x * 64 + (wave >> 1) * 32; c0 = (wave & 1) * 64; }
    else               { r0 = blockIdx.x * 32;                    c0 = wave * 64; }

    f32x4 acc[2][4];
    #pragma unroll
    for (int rb = 0; rb < 2; ++rb)
        #pragma unroll
        for (int cb = 0; cb < 4; ++cb)
            acc[rb][cb] = (f32x4){0.f, 0.f, 0.f, 0.f};

    const float* a0 = in + (size_t)(r0 + lrow) * C_ + lk8;
    const float* a1 = in + (size_t)(r0 + 16 + lrow) * C_ + lk8;

    #pragma unroll
    for (int ks = 0; ks < 4; ++ks) {
        bf16x8 ah[2], al[2];
        #pragma unroll
        for (int rb = 0; rb < 2; ++rb) {
            const float* ap = (rb ? a1 : a0) + ks * 32;
            const float4 v0 = *(const float4*)ap;
            const float4 v1 = *(const float4*)(ap + 4);
            const float f[8] = {v0.x, v0.y, v0.z, v0.w, v1.x, v1.y, v1.z, v1.w};
            #pragma unroll
            for (int i = 0; i < 8; ++i) {
                short h, l; split_bf16(f[i], h, l);
                ah[rb][i] = h; al[rb][i] = l;
            }
        }
        #pragma unroll
        for (int cb = 0; cb < 4; ++cb) {
            const size_t boff = (size_t)(c0 + cb * 16 + lrow) * C_ + ks * 32 + lk8;
            const bf16x8 bh = *(const bf16x8*)(whi + boff);
            const bf16x8 bl = *(const bf16x8*)(wlo + boff);
            #pragma unroll
            for (int rb = 0; rb < 2; ++rb) {
                f32x4 t = acc[rb][cb];
                t = mfma16(ah[rb], bh, t);
                t = mfma16(ah[rb], bl, t);
                t = mfma16(al[rb], bh, t);
                acc[rb][cb] = t;
            }
        }
    }
    // epilogue: C/D layout col=lane&15, row=(lane>>4)*4+reg  [m89-verified]
    #pragma unroll
    for (int rb = 0; rb < 2; ++rb)
        #pragma unroll
        for (int cb = 0; cb < 4; ++cb) {
            const int col = c0 + cb * 16 + lrow;
            float* op; int colo;
            if constexpr (EPI) { op = out0; colo = col; }
            else { const bool toz = (c0 + cb * 16) >= 128; op = toz ? out1 : out0; colo = col & 127; }
            const float bz = EPI ? bias[colo] : 0.f;
            #pragma unroll
            for (int j = 0; j < 4; ++j) {
                const size_t row = (size_t)r0 + rb * 16 + (lane >> 4) * 4 + j;
                float v = acc[rb][cb][j] + bz;
                if constexpr (EPI) v += resid[row * C_ + colo];
                op[row * C_ + colo] = v;
            }
        }
}

// ============================================================================
// MFMA x_dbl: xd[ST x 32] = u[ST x 128] @ xw_pad[32 x 128]^T  (split-bf16)
// Wave tile 32x32; block = 4 waves = 128 rows; grid = 128 blocks.
// ============================================================================
__global__ __launch_bounds__(256) void k_xdbl(const float* __restrict__ u,
        const unsigned short* __restrict__ xwhi, const unsigned short* __restrict__ xwlo,
        float* __restrict__ xd) {
    const int tid  = threadIdx.x;
    const int wave = tid >> 6, lane = tid & 63;
    const int lrow = lane & 15;
    const int lk8  = (lane >> 4) << 3;
    const int r0   = blockIdx.x * 128 + wave * 32;

    f32x4 acc[2][2];
    #pragma unroll
    for (int rb = 0; rb < 2; ++rb)
        #pragma unroll
        for (int cb = 0; cb < 2; ++cb)
            acc[rb][cb] = (f32x4){0.f, 0.f, 0.f, 0.f};

    const float* a0 = u + (size_t)(r0 + lrow) * C_ + lk8;
    const float* a1 = u + (size_t)(r0 + 16 + lrow) * C_ + lk8;

    #pragma unroll
    for (int ks = 0; ks < 4; ++ks) {
        bf16x8 ah[2], al[2];
        #pragma unroll
        for (int rb = 0; rb < 2; ++rb) {
            const float* ap = (rb ? a1 : a0) + ks * 32;
            const float4 v0 = *(const float4*)ap;
            const float4 v1 = *(const float4*)(ap + 4);
            const float f[8] = {v0.x, v0.y, v0.z, v0.w, v1.x, v1.y, v1.z, v1.w};
            #pragma unroll
            for (int i = 0; i < 8; ++i) {
                short h, l; split_bf16(f[i], h, l);
                ah[rb][i] = h; al[rb][i] = l;
            }
        }
        #pragma unroll
        for (int cb = 0; cb < 2; ++cb) {
            const size_t boff = (size_t)(cb * 16 + lrow) * C_ + ks * 32 + lk8;
            const bf16x8 bh = *(const bf16x8*)(xwhi + boff);
            const bf16x8 bl = *(const bf16x8*)(xwlo + boff);
            #pragma unroll
            for (int rb = 0; rb < 2; ++rb) {
                f32x4 t = acc[rb][cb];
                t = mfma16(ah[rb], bh, t);
                t = mfma16(ah[rb], bl, t);
                t = mfma16(al[rb], bh, t);
                acc[rb][cb] = t;
            }
        }
    }
    #pragma unroll
    for (int rb = 0; rb < 2; ++rb)
        #pragma unroll
        for (int cb = 0; cb < 2; ++cb) {
            const int col = cb * 16 + lrow;
            #pragma unroll
            for (int j = 0; j < 4; ++j) {
                const int row = r0 + rb * 16 + (lane >> 4) * 4 + j;
                xd[(size_t)row * 32 + col] = acc[rb][cb][j];
            }
        }
}

// ============================================================================
// delta/Bs/Cs from xd: fully parallel. Block = 2 rows x 128 c.
// ============================================================================
__global__ __launch_bounds__(256) void k_dbc(const float* __restrict__ xd,
        const float* __restrict__ prompt, const float* __restrict__ dtw,
        const float* __restrict__ dtb, float* __restrict__ delta,
        float* __restrict__ Bsv, float* __restrict__ Csv) {
    const int tid = threadIdx.x;
    const int g = blockIdx.x * 2 + (tid >> 7);     // global active row 0..16383
    const int c = tid & 127;
    const float* xr = xd + (size_t)g * 32;
    float wreg[8];
    *(float4*)&wreg[0] = *(const float4*)(dtw + c*8);
    *(float4*)&wreg[4] = *(const float4*)(dtw + c*8 + 4);
    float dd = dtb[c];
    #pragma unroll
    for (int r = 0; r < 8; ++r) dd += xr[r] * wreg[r];     // broadcast loads
    delta[(size_t)g * C_ + c] = softplus_f(dd);
    if (c < 8) {
        Bsv[(size_t)g * N_ + c] = xr[8 + c];
    } else if (c < 16) {
        const int n = c - 8;
        const int b = g >> 12, s = g & 4095;
        const int l = ((s >> 6) << 7) | (s & 63);
        Csv[(size_t)g * N_ + n] = xr[16 + n] + prompt[((size_t)b*L_ + l)*N_ + n];
    }
}

// ============================================================================
// 2-level Haar DWT: x_proc (B,L,C) -> bands1 [B][3][64][64][C] + compact u
// ============================================================================
__global__ __launch_bounds__(128) void k_dwt(const float* __restrict__ xp,
        float* __restrict__ bands, float* __restrict__ u) {
    const int c = threadIdx.x;
    const int bid = blockIdx.x;
    const int b = bid >> 10, p = (bid >> 5) & 31, q = bid & 31;
    float v[4][4];
    const size_t base = (size_t)b * L_ * C_ + c;
    #pragma unroll
    for (int i = 0; i < 4; ++i)
        #pragma unroll
        for (int j = 0; j < 4; ++j)
            v[i][j] = xp[base + (size_t)(((p<<2)+i)*W_ + (q<<2)+j) * C_];
    const size_t bstride = (size_t)64*64*C_;
    float ll[2][2];
    #pragma unroll
    for (int di = 0; di < 2; ++di)
        #pragma unroll
        for (int dj = 0; dj < 2; ++dj) {
            const float a  = v[2*di][2*dj],   bb = v[2*di][2*dj+1];
            const float cc = v[2*di+1][2*dj], dd = v[2*di+1][2*dj+1];
            ll[di][dj]     = (a+bb+cc+dd)*0.5f;
            const float lh = (a+bb-cc-dd)*0.5f;
            const float hl = (a-bb+cc-dd)*0.5f;
            const float hh = (a-bb-cc+dd)*0.5f;
            const int i1 = (p<<1)+di, j1 = (q<<1)+dj;
            const size_t bb0 = (((size_t)b*3*64 + i1)*64 + j1)*C_ + c;
            bands[bb0]             = lh;
            bands[bb0 +   bstride] = hl;
            bands[bb0 + 2*bstride] = hh;
        }
    const float a = ll[0][0], bb = ll[0][1], cc = ll[1][0], dd = ll[1][1];
    const float l2  = (a+bb+cc+dd)*0.5f;
    const float lh2 = (a+bb-cc-dd)*0.5f;
    const float hl2 = (a-bb+cc-dd)*0.5f;
    const float hh2 = (a-bb-cc+dd)*0.5f;
    const size_t ub = (size_t)b*LS_*C_ + c;
    u[ub + (size_t)((p<<6)+q)*C_]          = l2;
    u[ub + (size_t)((p<<6)+32+q)*C_]       = lh2;
    u[ub + (size_t)(((32+p)<<6)+q)*C_]     = hl2;
    u[ub + (size_t)(((32+p)<<6)+32+q)*C_]  = hh2;
}

// ============================================================================
// Scan pass 1: per (b,c,chunk) summary
// ============================================================================
__global__ __launch_bounds__(256) void k_scan1(const float* __restrict__ delta,
        const float* __restrict__ u, const float* __restrict__ Bsv,
        const float* __restrict__ Alog, float* __restrict__ dsum, float* __restrict__ hend) {
    const int tid = threadIdx.x;
    const int b = blockIdx.x >> 7, k2 = blockIdx.x & 127;
    const int k = (k2 << 1) | (tid >> 7);
    const int c = tid & 127;
    float al[8];
    *(float4*)&al[0] = *(const float4*)(Alog + c*8);
    *(float4*)&al[4] = *(const float4*)(Alog + c*8 + 4);
    float an[8];
    #pragma unroll
    for (int n = 0; n < 8; ++n) an[n] = -__expf(al[n]);
    float h[8] = {0,0,0,0,0,0,0,0};
    float cum = 0.f;
    const int s0 = k << 4;
    for (int t = 0; t < CS_; ++t) {
        const int s = s0 + t;
        const size_t base = ((size_t)b*LS_ + s)*C_ + c;
        const float d  = delta[base];
        const float uu = u[base];
        float bv[8];
        const float4* bp = (const float4*)(Bsv + ((size_t)b*LS_ + s)*N_);
        *(float4*)&bv[0] = bp[0];
        *(float4*)&bv[4] = bp[1];
        cum += d;
        const float du = d * uu;
        #pragma unroll
        for (int n = 0; n < 8; ++n)
            h[n] = __expf(d*an[n])*h[n] + bv[n]*du;
    }
    const size_t idx = (size_t)(b*NC_ + k)*C_ + c;
    dsum[idx] = cum;
    *(float4*)(hend + idx*N_)     = make_float4(h[0],h[1],h[2],h[3]);
    *(float4*)(hend + idx*N_ + 4) = make_float4(h[4],h[5],h[6],h[7]);
}

// ============================================================================
// Scan pass 2: serial combine, double-buffered batch-16 prefetch
// ============================================================================
#define KB_ 16
__global__ __launch_bounds__(256) void k_comb(const float* __restrict__ dsum,
        const float* __restrict__ hend, const float* __restrict__ Alog,
        const float* __restrict__ dtb, float* __restrict__ hin) {
    const int g = blockIdx.x * 256 + threadIdx.x;   // 0..4095
    const int b = g >> 10;
    const int c = (g >> 3) & 127;
    const int n = g & 7;
    const float a  = -__expf(Alog[c*N_ + n]);
    const float d0 = softplus_f(dtb[c]);
    const float dz = __expf(a * (64.f * d0));
    float carry = 0.f;
    float ea[KB_], ha[KB_], eb[KB_], hb[KB_];
    auto LOAD = [&](int kb, float* e, float* hv) {
        #pragma unroll
        for (int j = 0; j < KB_; ++j) {
            const size_t idx = (size_t)(b*NC_ + kb + j)*C_ + c;
            e[j]  = a * dsum[idx];
            hv[j] = hend[idx*N_ + n];
        }
    };
    auto CHAIN = [&](int kb, const float* e, const float* hv) {
        #pragma unroll
        for (int j = 0; j < KB_; ++j) {
            const int k = kb + j;
            if (k && !(k & 3)) carry *= dz;
            hin[((size_t)(b*NC_ + k)*C_ + c)*N_ + n] = carry;
            carry = __expf(e[j])*carry + hv[j];
        }
    };
    LOAD(0, ea, ha);
    for (int kb = 0; kb < NC_; kb += 2*KB_) {
        LOAD(kb + KB_, eb, hb);
        CHAIN(kb, ea, ha);
        if (kb + 2*KB_ < NC_) LOAD(kb + 2*KB_, ea, ha);
        CHAIN(kb + KB_, eb, hb);
    }
}

// ============================================================================
// Scan pass 3: re-run each chunk from true h_in -> h11
// ============================================================================
__global__ __launch_bounds__(256) void k_scan2(const float* __restrict__ delta,
        const float* __restrict__ u, const float* __restrict__ Bsv,
        const float* __restrict__ Csv, const float* __restrict__ Alog,
        const float* __restrict__ Ds, const float* __restrict__ hin,
        float* __restrict__ h11) {
    const int tid = threadIdx.x;
    const int b = blockIdx.x >> 7, k2 = blockIdx.x & 127;
    const int k = (k2 << 1) | (tid >> 7);
    const int c = tid & 127;
    float al[8];
    *(float4*)&al[0] = *(const float4*)(Alog + c*8);
    *(float4*)&al[4] = *(const float4*)(Alog + c*8 + 4);
    float an[8];
    #pragma unroll
    for (int n = 0; n < 8; ++n) an[n] = -__expf(al[n]);
    float h[8];
    const float4* hp = (const float4*)(hin + ((size_t)(b*NC_ + k)*C_ + c)*N_);
    *(float4*)&h[0] = hp[0];
    *(float4*)&h[4] = hp[1];
    const float dsc = Ds[c];
    const int s0 = k << 4;
    for (int t = 0; t < CS_; ++t) {
        const int s = s0 + t;
        const size_t base = ((size_t)b*LS_ + s)*C_ + c;
        const float d  = delta[base];
        const float uu = u[base];
        float bv[8], cv[8];
        const float4* bp = (const float4*)(Bsv + ((size_t)b*LS_ + s)*N_);
        const float4* cp = (const float4*)(Csv + ((size_t)b*LS_ + s)*N_);
        *(float4*)&bv[0] = bp[0];
        *(float4*)&bv[4] = bp[1];
        *(float4*)&cv[0] = cp[0];
        *(float4*)&cv[4] = cp[1];
        const float du = d * uu;
        float y = uu * dsc;
        #pragma unroll
        for (int n = 0; n < 8; ++n) {
            h[n] = __expf(d*an[n])*h[n] + bv[n]*du;
            y += h[n] * cv[n];
        }
        h11[base] = y;
    }
}

// ============================================================================
// Fused 2-level inverse Haar DWT + LayerNorm + SiLU gate -> y
// ============================================================================
__global__ __launch_bounds__(128) void k_idwt_ln(const float* __restrict__ h11,
        const float* __restrict__ bands, const float* __restrict__ z,
        const float* __restrict__ gamma, const float* __restrict__ beta,
        float* __restrict__ yout) {
    __shared__ float vb[16][129];
    __shared__ float stat[16][2];
    const int c = threadIdx.x;
    const int bid = blockIdx.x;
    const int b = bid >> 10, p = (bid >> 5) & 31, q = bid & 31;
    const size_t ub = (size_t)b*LS_*C_ + c;
    const float l2  = h11[ub + (size_t)((p<<6)+q)*C_];
    const float lh2 = h11[ub + (size_t)((p<<6)+32+q)*C_];
    const float hl2 = h11[ub + (size_t)(((32+p)<<6)+q)*C_];
    const float hh2 = h11[ub + (size_t)(((32+p)<<6)+32+q)*C_];
    float yl1[2][2];
    yl1[0][0] = (l2+lh2+hl2+hh2)*0.5f;
    yl1[0][1] = (l2+lh2-hl2-hh2)*0.5f;
    yl1[1][0] = (l2-lh2+hl2-hh2)*0.5f;
    yl1[1][1] = (l2-lh2-hl2+hh2)*0.5f;
    const size_t bstride = (size_t)64*64*C_;
    float v[16];
    #pragma unroll
    for (int di = 0; di < 2; ++di)
        #pragma unroll
        for (int dj = 0; dj < 2; ++dj) {
            const int i1 = (p<<1)+di, j1 = (q<<1)+dj;
            const size_t bb0 = (((size_t)b*3*64 + i1)*64 + j1)*C_ + c;
            const float lh = bands[bb0];
            const float hl = bands[bb0 +   bstride];
            const float hh = bands[bb0 + 2*bstride];
            const float ll = yl1[di][dj];
            v[(2*di+0)*4 + 2*dj+0] = (ll+lh+hl+hh)*0.5f;
            v[(2*di+0)*4 + 2*dj+1] = (ll+lh-hl-hh)*0.5f;
            v[(2*di+1)*4 + 2*dj+0] = (ll-lh+hl-hh)*0.5f;
            v[(2*di+1)*4 + 2*dj+1] = (ll-lh-hl+hh)*0.5f;
        }
    #pragma unroll
    for (int p16 = 0; p16 < 16; ++p16) vb[p16][c] = v[p16];
    __syncthreads();
    {
        const int pp = c >> 3, gg = c & 7;
        float s = 0.f, ss = 0.f;
        #pragma unroll
        for (int i = 0; i < 16; ++i) {
            const float x = vb[pp][gg*16 + i];
            s += x; ss += x*x;
        }
        s += __shfl_xor(s, 1); ss += __shfl_xor(ss, 1);
        s += __shfl_xor(s, 2); ss += __shfl_xor(ss, 2);
        s += __shfl_xor(s, 4); ss += __shfl_xor(ss, 4);
        if (gg == 0) { stat[pp][0] = s; stat[pp][1] = ss; }
    }
    __syncthreads();
    const float gm = gamma[c], bt = beta[c];
    #pragma unroll
    for (int p16 = 0; p16 < 16; ++p16) {
        const int lr = p16 >> 2, lc = p16 & 3;
        const size_t l = (size_t)((p<<2)+lr)*W_ + (q<<2)+lc;
        const float mu  = stat[p16][0] * 0.0078125f;
        const float var = stat[p16][1] * 0.0078125f - mu*mu;
        const float ri  = rsqrtf(var + 1e-5f);
        float y = (v[p16] - mu)*ri*gm + bt;
        const float zv = z[((size_t)b*L_ + l)*C_ + c];
        y *= zv / (1.f + __expf(-zv));
        yout[((size_t)b*L_ + l)*C_ + c] = y;
    }
}

// ============================================================================
extern "C" void kernel_launch(void* const* d_in, const int* in_sizes, int n_in,
                              void* d_out, int out_size, void* d_ws, size_t ws_size,
                              hipStream_t stream) {
    (void)in_sizes; (void)n_in; (void)out_size; (void)ws_size;
    const float* x      = (const float*)d_in[0];
    const float* prompt = (const float*)d_in[1];
    const float* in_w   = (const float*)d_in[2];
    const float* x_w    = (const float*)d_in[3];
    const float* dt_w   = (const float*)d_in[4];
    const float* dt_b   = (const float*)d_in[5];
    const float* A_logs = (const float*)d_in[6];
    const float* Ds     = (const float*)d_in[7];
    const float* gam    = (const float*)d_in[8];
    const float* bet    = (const float*)d_in[9];
    const float* out_w  = (const float*)d_in[10];
    const float* out_b  = (const float*)d_in[11];
    float* wsp   = (float*)d_ws;
    float* xproc = wsp + OFF_XPROC;   // later reused for gated y
    float* z     = wsp + OFF_Z;
    float* bands = wsp + OFF_BANDS;
    float* u     = wsp + OFF_U;
    float* delta = wsp + OFF_DELTA;
    float* Bs    = wsp + OFF_BS;
    float* Cs    = wsp + OFF_CS;
    float* dsum  = wsp + OFF_DSUM;
    float* hend  = wsp + OFF_HEND;
    float* hin   = wsp + OFF_HIN;
    float* h11   = wsp + OFF_H11;
    float* xd    = wsp + OFF_XDBL;
    unsigned short* wq = (unsigned short*)(wsp + OFF_WCVT);
    unsigned short* whi_in  = wq;
    unsigned short* wlo_in  = wq + 32768;
    unsigned short* whi_out = wq + 65536;
    unsigned short* wlo_out = wq + 81920;
    unsigned short* whi_xw  = wq + 98304;
    unsigned short* wlo_xw  = wq + 102400;
    float* out   = (float*)d_out;

    // 0) split weights into bf16 hi/lo
    k_cvt<<<208, 256, 0, stream>>>(in_w, out_w, x_w, wq);
    // 1) in_proj GEMM (MFMA split-bf16) -> x_proc, z
    k_gemm_mfma<false><<<2048, 256, 0, stream>>>(x, whi_in, wlo_in, xproc, z, nullptr, nullptr);
    // 2) 2-level DWT -> bands1 + compact active-region u
    k_dwt<<<4096, 128, 0, stream>>>(xproc, bands, u);
    // 3a) x_dbl = u @ x_proj^T (MFMA)
    k_xdbl<<<128, 256, 0, stream>>>(u, whi_xw, wlo_xw, xd);
    // 3b) delta / Bs / Cs (fully parallel)
    k_dbc<<<8192, 256, 0, stream>>>(xd, prompt, dt_w, dt_b, delta, Bs, Cs);
    // 4) chunked scan: summaries
    k_scan1<<<512, 256, 0, stream>>>(delta, u, Bs, A_logs, dsum, hend);
    // 5) serial combine across chunk boundaries
    k_comb<<<16, 256, 0, stream>>>(dsum, hend, A_logs, dt_b, hin);
    // 6) re-scan with true initial states -> h11
    k_scan2<<<512, 256, 0, stream>>>(delta, u, Bs, Cs, A_logs, Ds, hin, h11);
    // 7) fused inverse DWT + LayerNorm + SiLU gate -> y (xproc buffer)
    k_idwt_ln<<<4096, 128, 0, stream>>>(h11, bands, z, gam, bet, xproc);
    // 8) out_proj GEMM + bias + residual -> d_out
    k_gemm_mfma<true><<<1024, 256, 0, stream>>>(xproc, whi_out, wlo_out, out, nullptr, out_b, x);
}

// Round 4
// 232.010 us; speedup vs baseline: 1.4990x; 1.1120x over previous
//
#include <hip/hip_runtime.h>

// Problem constants (fixed by setup_inputs)
#define B_   4
#define H_   128
#define W_   128
#define L_   (H_*W_)        // 16384
#define C_   128
#define N_   8
#define R_   8
#define LS_  4096           // active scan positions per batch (64x64 top-left region)
#define CS_  16             // scan chunk length (steps)
#define NC_  256            // chunks per (b,c) = LS_/CS_
#define ST_  (B_*LS_)       // 16384 total active rows

// ---- workspace layout (in floats) ----
#define OFF_XPROC 0ull
#define OFF_Z     (OFF_XPROC + (size_t)B_*L_*C_)
#define OFF_BANDS (OFF_Z     + (size_t)B_*L_*C_)                 // bands1: [B][3][64][64][C]
#define OFF_U     (OFF_BANDS + (size_t)B_*3*64*64*C_)            // u  [B][4096][C]
#define OFF_DELTA (OFF_U     + (size_t)B_*LS_*C_)
#define OFF_BS    (OFF_DELTA + (size_t)B_*LS_*C_)                // [B][4096][8]
#define OFF_CS    (OFF_BS    + (size_t)B_*LS_*N_)
#define OFF_DSUM  (OFF_CS    + (size_t)B_*LS_*N_)                // [B][NC][C]
#define OFF_HEND  (OFF_DSUM  + (size_t)B_*NC_*C_)                // [B][NC][C][8]
#define OFF_HIN   (OFF_HEND  + (size_t)B_*NC_*C_*N_)
#define OFF_H11   (OFF_HIN   + (size_t)B_*NC_*C_*N_)             // [B][4096][C]
#define OFF_XDBL  (OFF_H11   + (size_t)B_*LS_*C_)                // [ST][32] fp32
#define OFF_WCVT  (OFF_XDBL  + (size_t)ST_*32)                   // ushort region: split weights

typedef __attribute__((ext_vector_type(8))) short bf16x8;
typedef __attribute__((ext_vector_type(4))) float f32x4;

__device__ __forceinline__ float softplus_f(float x) {
    return (x > 20.f) ? x : log1pf(__expf(x));
}

// split fp32 into bf16 hi (round-nearest) + bf16 lo (truncated residual)
__device__ __forceinline__ void split_bf16(float x, short& h, short& l) {
    const unsigned u  = __float_as_uint(x);
    const unsigned hr = (u + 0x7FFFu + ((u >> 16) & 1u)) >> 16;
    h = (short)hr;
    const float hf = __uint_as_float(hr << 16);
    l = (short)(__float_as_uint(x - hf) >> 16);
}

__device__ __forceinline__ f32x4 mfma16(bf16x8 a, bf16x8 b, f32x4 c) {
    return __builtin_amdgcn_mfma_f32_16x16x32_bf16(a, b, c, 0, 0, 0);
}

// ============================================================================
// Weight split: in_proj (256x128), out_proj (128x128), x_proj (24x128 pad 32)
// ============================================================================
__global__ __launch_bounds__(256) void k_cvt(const float* __restrict__ w_in,
        const float* __restrict__ w_out, const float* __restrict__ xw,
        unsigned short* __restrict__ wq) {
    const int i = blockIdx.x * 256 + threadIdx.x;   // 0..53247
    float v; unsigned short *hi, *lo; int idx;
    if (i < 32768)      { v = w_in[i];          hi = wq;         lo = wq + 32768;  idx = i; }
    else if (i < 49152) { v = w_out[i - 32768]; hi = wq + 65536; lo = wq + 81920;  idx = i - 32768; }
    else {
        idx = i - 49152;                         // 0..4095 over [32][128]
        v = (idx < 24*128) ? xw[idx] : 0.f;      // zero-pad rows 24..31
        hi = wq + 98304; lo = wq + 102400;
    }
    short h, l; split_bf16(v, h, l);
    hi[idx] = (unsigned short)h;
    lo[idx] = (unsigned short)l;
}

// ============================================================================
// MFMA split-bf16 GEMM, weights-in-registers, persistent grid-stride.
// out[M x NJ] = in[M x 128] @ w[NJ x 128]^T
//   !EPI: NJ=256, 4 waves side-by-side (wave tile 32x64), chunk = 32 rows,
//         cols 0-127 -> out0 (xproc), 128-255 -> out1 (z).
//   EPI : NJ=128, 2x2 waves, chunk = 64 rows, + bias + resid -> out0.
// Swapped-operand MFMA (W first) => lane's 4 acc regs = 4 consecutive out
// cols of ONE row => float4 stores.
// ============================================================================
template<bool EPI>
__global__ __launch_bounds__(256, 2) void k_gemm2(const float* __restrict__ in,
        const unsigned short* __restrict__ whi, const unsigned short* __restrict__ wlo,
        float* __restrict__ out0, float* __restrict__ out1,
        const float* __restrict__ bias, const float* __restrict__ resid) {
    const int tid  = threadIdx.x;
    const int wave = tid >> 6, lane = tid & 63;
    const int lrow = lane & 15;           // weight-row / A-row lane index
    const int lk8  = (lane >> 4) << 3;    // k-offset within 32-k step
    const int oc4  = (lane >> 4) << 2;    // output-col sub-offset for stores

    int c0, wr;
    if constexpr (EPI) { c0 = (wave & 1) * 64; wr = wave >> 1; }
    else               { c0 = wave * 64;       wr = 0; }

    // ---- preload this wave's B panel (64 cols x K=128, hi+lo) into regs ----
    bf16x8 Bh[4][4], Bl[4][4];
    #pragma unroll
    for (int cb = 0; cb < 4; ++cb)
        #pragma unroll
        for (int ks = 0; ks < 4; ++ks) {
            const size_t boff = (size_t)(c0 + cb * 16 + lrow) * C_ + ks * 32 + lk8;
            Bh[cb][ks] = *(const bf16x8*)(whi + boff);
            Bl[cb][ks] = *(const bf16x8*)(wlo + boff);
        }

    const int nch = EPI ? 1024 : 2048;    // chunks of (EPI?64:32) rows
    for (int ch = blockIdx.x; ch < nch; ch += gridDim.x) {
        const int r0 = EPI ? (ch * 64 + wr * 32) : ch * 32;
        f32x4 acc[2][4];
        #pragma unroll
        for (int rb = 0; rb < 2; ++rb)
            #pragma unroll
            for (int cb = 0; cb < 4; ++cb)
                acc[rb][cb] = (f32x4){0.f, 0.f, 0.f, 0.f};

        #pragma unroll
        for (int rb = 0; rb < 2; ++rb) {
            const float* ap = in + (size_t)(r0 + rb * 16 + lrow) * C_;
            float4 ar[8];
            #pragma unroll
            for (int ks = 0; ks < 4; ++ks) {
                ar[2*ks]   = *(const float4*)(ap + ks * 32 + lk8);
                ar[2*ks+1] = *(const float4*)(ap + ks * 32 + lk8 + 4);
            }
            #pragma unroll
            for (int ks = 0; ks < 4; ++ks) {
                const float f[8] = {ar[2*ks].x, ar[2*ks].y, ar[2*ks].z, ar[2*ks].w,
                                    ar[2*ks+1].x, ar[2*ks+1].y, ar[2*ks+1].z, ar[2*ks+1].w};
                bf16x8 ah, al;
                #pragma unroll
                for (int i = 0; i < 8; ++i) {
                    short h, l; split_bf16(f[i], h, l);
                    ah[i] = h; al[i] = l;
                }
                #pragma unroll
                for (int cb = 0; cb < 4; ++cb) {
                    f32x4 t = acc[rb][cb];
                    t = mfma16(Bh[cb][ks], ah, t);   // W first: transposed frag
                    t = mfma16(Bl[cb][ks], ah, t);
                    t = mfma16(Bh[cb][ks], al, t);
                    acc[rb][cb] = t;
                }
            }
        }
        // ---- epilogue: float4 per (rb,cb): row=r0+rb*16+lrow, col=c0+cb*16+oc4 ----
        #pragma unroll
        for (int rb = 0; rb < 2; ++rb) {
            const size_t row = (size_t)r0 + rb * 16 + lrow;
            #pragma unroll
            for (int cb = 0; cb < 4; ++cb) {
                const int col = c0 + cb * 16 + oc4;
                f32x4 v = acc[rb][cb];
                if constexpr (EPI) {
                    const float4 bz = *(const float4*)(bias + col);
                    const float4 rv = *(const float4*)(resid + row * C_ + col);
                    v[0] += bz.x + rv.x; v[1] += bz.y + rv.y;
                    v[2] += bz.z + rv.z; v[3] += bz.w + rv.w;
                    *(f32x4*)(out0 + row * C_ + col) = v;
                } else {
                    float* op = (c0 >= 128) ? out1 : out0;
                    *(f32x4*)(op + row * C_ + (col & 127)) = v;
                }
            }
        }
    }
}

// ============================================================================
// MFMA x_dbl: xd[ST x 32] = u[ST x 128] @ xw_pad[32 x 128]^T  (split-bf16)
// ============================================================================
__global__ __launch_bounds__(256) void k_xdbl(const float* __restrict__ u,
        const unsigned short* __restrict__ xwhi, const unsigned short* __restrict__ xwlo,
        float* __restrict__ xd) {
    const int tid  = threadIdx.x;
    const int wave = tid >> 6, lane = tid & 63;
    const int lrow = lane & 15;
    const int lk8  = (lane >> 4) << 3;
    const int r0   = blockIdx.x * 128 + wave * 32;

    f32x4 acc[2][2];
    #pragma unroll
    for (int rb = 0; rb < 2; ++rb)
        #pragma unroll
        for (int cb = 0; cb < 2; ++cb)
            acc[rb][cb] = (f32x4){0.f, 0.f, 0.f, 0.f};

    const float* a0 = u + (size_t)(r0 + lrow) * C_ + lk8;
    const float* a1 = u + (size_t)(r0 + 16 + lrow) * C_ + lk8;

    #pragma unroll
    for (int ks = 0; ks < 4; ++ks) {
        bf16x8 ah[2], al[2];
        #pragma unroll
        for (int rb = 0; rb < 2; ++rb) {
            const float* ap = (rb ? a1 : a0) + ks * 32;
            const float4 v0 = *(const float4*)ap;
            const float4 v1 = *(const float4*)(ap + 4);
            const float f[8] = {v0.x, v0.y, v0.z, v0.w, v1.x, v1.y, v1.z, v1.w};
            #pragma unroll
            for (int i = 0; i < 8; ++i) {
                short h, l; split_bf16(f[i], h, l);
                ah[rb][i] = h; al[rb][i] = l;
            }
        }
        #pragma unroll
        for (int cb = 0; cb < 2; ++cb) {
            const size_t boff = (size_t)(cb * 16 + lrow) * C_ + ks * 32 + lk8;
            const bf16x8 bh = *(const bf16x8*)(xwhi + boff);
            const bf16x8 bl = *(const bf16x8*)(xwlo + boff);
            #pragma unroll
            for (int rb = 0; rb < 2; ++rb) {
                f32x4 t = acc[rb][cb];
                t = mfma16(ah[rb], bh, t);
                t = mfma16(ah[rb], bl, t);
                t = mfma16(al[rb], bh, t);
                acc[rb][cb] = t;
            }
        }
    }
    #pragma unroll
    for (int rb = 0; rb < 2; ++rb)
        #pragma unroll
        for (int cb = 0; cb < 2; ++cb) {
            const int col = cb * 16 + lrow;
            #pragma unroll
            for (int j = 0; j < 4; ++j) {
                const int row = r0 + rb * 16 + (lane >> 4) * 4 + j;
                xd[(size_t)row * 32 + col] = acc[rb][cb][j];
            }
        }
}

// ============================================================================
// delta/Bs/Cs from xd: fully parallel. Block = 2 rows x 128 c.
// ============================================================================
__global__ __launch_bounds__(256) void k_dbc(const float* __restrict__ xd,
        const float* __restrict__ prompt, const float* __restrict__ dtw,
        const float* __restrict__ dtb, float* __restrict__ delta,
        float* __restrict__ Bsv, float* __restrict__ Csv) {
    const int tid = threadIdx.x;
    const int g = blockIdx.x * 2 + (tid >> 7);     // global active row 0..16383
    const int c = tid & 127;
    const float* xr = xd + (size_t)g * 32;
    float wreg[8];
    *(float4*)&wreg[0] = *(const float4*)(dtw + c*8);
    *(float4*)&wreg[4] = *(const float4*)(dtw + c*8 + 4);
    float dd = dtb[c];
    #pragma unroll
    for (int r = 0; r < 8; ++r) dd += xr[r] * wreg[r];     // broadcast loads
    delta[(size_t)g * C_ + c] = softplus_f(dd);
    if (c < 8) {
        Bsv[(size_t)g * N_ + c] = xr[8 + c];
    } else if (c < 16) {
        const int n = c - 8;
        const int b = g >> 12, s = g & 4095;
        const int l = ((s >> 6) << 7) | (s & 63);
        Csv[(size_t)g * N_ + n] = xr[16 + n] + prompt[((size_t)b*L_ + l)*N_ + n];
    }
}

// ============================================================================
// 2-level Haar DWT: x_proc (B,L,C) -> bands1 [B][3][64][64][C] + compact u
// ============================================================================
__global__ __launch_bounds__(128) void k_dwt(const float* __restrict__ xp,
        float* __restrict__ bands, float* __restrict__ u) {
    const int c = threadIdx.x;
    const int bid = blockIdx.x;
    const int b = bid >> 10, p = (bid >> 5) & 31, q = bid & 31;
    float v[4][4];
    const size_t base = (size_t)b * L_ * C_ + c;
    #pragma unroll
    for (int i = 0; i < 4; ++i)
        #pragma unroll
        for (int j = 0; j < 4; ++j)
            v[i][j] = xp[base + (size_t)(((p<<2)+i)*W_ + (q<<2)+j) * C_];
    const size_t bstride = (size_t)64*64*C_;
    float ll[2][2];
    #pragma unroll
    for (int di = 0; di < 2; ++di)
        #pragma unroll
        for (int dj = 0; dj < 2; ++dj) {
            const float a  = v[2*di][2*dj],   bb = v[2*di][2*dj+1];
            const float cc = v[2*di+1][2*dj], dd = v[2*di+1][2*dj+1];
            ll[di][dj]     = (a+bb+cc+dd)*0.5f;
            const float lh = (a+bb-cc-dd)*0.5f;
            const float hl = (a-bb+cc-dd)*0.5f;
            const float hh = (a-bb-cc+dd)*0.5f;
            const int i1 = (p<<1)+di, j1 = (q<<1)+dj;
            const size_t bb0 = (((size_t)b*3*64 + i1)*64 + j1)*C_ + c;
            bands[bb0]             = lh;
            bands[bb0 +   bstride] = hl;
            bands[bb0 + 2*bstride] = hh;
        }
    const float a = ll[0][0], bb = ll[0][1], cc = ll[1][0], dd = ll[1][1];
    const float l2  = (a+bb+cc+dd)*0.5f;
    const float lh2 = (a+bb-cc-dd)*0.5f;
    const float hl2 = (a-bb+cc-dd)*0.5f;
    const float hh2 = (a-bb-cc+dd)*0.5f;
    const size_t ub = (size_t)b*LS_*C_ + c;
    u[ub + (size_t)((p<<6)+q)*C_]          = l2;
    u[ub + (size_t)((p<<6)+32+q)*C_]       = lh2;
    u[ub + (size_t)(((32+p)<<6)+q)*C_]     = hl2;
    u[ub + (size_t)(((32+p)<<6)+32+q)*C_]  = hh2;
}

// ============================================================================
// Scan pass 1: per (b,c,chunk) summary
// ============================================================================
__global__ __launch_bounds__(256) void k_scan1(const float* __restrict__ delta,
        const float* __restrict__ u, const float* __restrict__ Bsv,
        const float* __restrict__ Alog, float* __restrict__ dsum, float* __restrict__ hend) {
    const int tid = threadIdx.x;
    const int b = blockIdx.x >> 7, k2 = blockIdx.x & 127;
    const int k = (k2 << 1) | (tid >> 7);
    const int c = tid & 127;
    float al[8];
    *(float4*)&al[0] = *(const float4*)(Alog + c*8);
    *(float4*)&al[4] = *(const float4*)(Alog + c*8 + 4);
    float an[8];
    #pragma unroll
    for (int n = 0; n < 8; ++n) an[n] = -__expf(al[n]);
    float h[8] = {0,0,0,0,0,0,0,0};
    float cum = 0.f;
    const int s0 = k << 4;
    for (int t = 0; t < CS_; ++t) {
        const int s = s0 + t;
        const size_t base = ((size_t)b*LS_ + s)*C_ + c;
        const float d  = delta[base];
        const float uu = u[base];
        float bv[8];
        const float4* bp = (const float4*)(Bsv + ((size_t)b*LS_ + s)*N_);
        *(float4*)&bv[0] = bp[0];
        *(float4*)&bv[4] = bp[1];
        cum += d;
        const float du = d * uu;
        #pragma unroll
        for (int n = 0; n < 8; ++n)
            h[n] = __expf(d*an[n])*h[n] + bv[n]*du;
    }
    const size_t idx = (size_t)(b*NC_ + k)*C_ + c;
    dsum[idx] = cum;
    *(float4*)(hend + idx*N_)     = make_float4(h[0],h[1],h[2],h[3]);
    *(float4*)(hend + idx*N_ + 4) = make_float4(h[4],h[5],h[6],h[7]);
}

// ============================================================================
// Scan pass 2: serial combine, double-buffered batch-16 prefetch
// ============================================================================
#define KB_ 16
__global__ __launch_bounds__(256) void k_comb(const float* __restrict__ dsum,
        const float* __restrict__ hend, const float* __restrict__ Alog,
        const float* __restrict__ dtb, float* __restrict__ hin) {
    const int g = blockIdx.x * 256 + threadIdx.x;   // 0..4095
    const int b = g >> 10;
    const int c = (g >> 3) & 127;
    const int n = g & 7;
    const float a  = -__expf(Alog[c*N_ + n]);
    const float d0 = softplus_f(dtb[c]);
    const float dz = __expf(a * (64.f * d0));
    float carry = 0.f;
    float ea[KB_], ha[KB_], eb[KB_], hb[KB_];
    auto LOAD = [&](int kb, float* e, float* hv) {
        #pragma unroll
        for (int j = 0; j < KB_; ++j) {
            const size_t idx = (size_t)(b*NC_ + kb + j)*C_ + c;
            e[j]  = a * dsum[idx];
            hv[j] = hend[idx*N_ + n];
        }
    };
    auto CHAIN = [&](int kb, const float* e, const float* hv) {
        #pragma unroll
        for (int j = 0; j < KB_; ++j) {
            const int k = kb + j;
            if (k && !(k & 3)) carry *= dz;
            hin[((size_t)(b*NC_ + k)*C_ + c)*N_ + n] = carry;
            carry = __expf(e[j])*carry + hv[j];
        }
    };
    LOAD(0, ea, ha);
    for (int kb = 0; kb < NC_; kb += 2*KB_) {
        LOAD(kb + KB_, eb, hb);
        CHAIN(kb, ea, ha);
        if (kb + 2*KB_ < NC_) LOAD(kb + 2*KB_, ea, ha);
        CHAIN(kb + KB_, eb, hb);
    }
}

// ============================================================================
// Scan pass 3: re-run each chunk from true h_in -> h11
// ============================================================================
__global__ __launch_bounds__(256) void k_scan2(const float* __restrict__ delta,
        const float* __restrict__ u, const float* __restrict__ Bsv,
        const float* __restrict__ Csv, const float* __restrict__ Alog,
        const float* __restrict__ Ds, const float* __restrict__ hin,
        float* __restrict__ h11) {
    const int tid = threadIdx.x;
    const int b = blockIdx.x >> 7, k2 = blockIdx.x & 127;
    const int k = (k2 << 1) | (tid >> 7);
    const int c = tid & 127;
    float al[8];
    *(float4*)&al[0] = *(const float4*)(Alog + c*8);
    *(float4*)&al[4] = *(const float4*)(Alog + c*8 + 4);
    float an[8];
    #pragma unroll
    for (int n = 0; n < 8; ++n) an[n] = -__expf(al[n]);
    float h[8];
    const float4* hp = (const float4*)(hin + ((size_t)(b*NC_ + k)*C_ + c)*N_);
    *(float4*)&h[0] = hp[0];
    *(float4*)&h[4] = hp[1];
    const float dsc = Ds[c];
    const int s0 = k << 4;
    for (int t = 0; t < CS_; ++t) {
        const int s = s0 + t;
        const size_t base = ((size_t)b*LS_ + s)*C_ + c;
        const float d  = delta[base];
        const float uu = u[base];
        float bv[8], cv[8];
        const float4* bp = (const float4*)(Bsv + ((size_t)b*LS_ + s)*N_);
        const float4* cp = (const float4*)(Csv + ((size_t)b*LS_ + s)*N_);
        *(float4*)&bv[0] = bp[0];
        *(float4*)&bv[4] = bp[1];
        *(float4*)&cv[0] = cp[0];
        *(float4*)&cv[4] = cp[1];
        const float du = d * uu;
        float y = uu * dsc;
        #pragma unroll
        for (int n = 0; n < 8; ++n) {
            h[n] = __expf(d*an[n])*h[n] + bv[n]*du;
            y += h[n] * cv[n];
        }
        h11[base] = y;
    }
}

// ============================================================================
// Fused 2-level inverse Haar DWT + LayerNorm + SiLU gate -> y
// ============================================================================
__global__ __launch_bounds__(128) void k_idwt_ln(const float* __restrict__ h11,
        const float* __restrict__ bands, const float* __restrict__ z,
        const float* __restrict__ gamma, const float* __restrict__ beta,
        float* __restrict__ yout) {
    __shared__ float vb[16][129];
    __shared__ float stat[16][2];
    const int c = threadIdx.x;
    const int bid = blockIdx.x;
    const int b = bid >> 10, p = (bid >> 5) & 31, q = bid & 31;
    const size_t ub = (size_t)b*LS_*C_ + c;
    const float l2  = h11[ub + (size_t)((p<<6)+q)*C_];
    const float lh2 = h11[ub + (size_t)((p<<6)+32+q)*C_];
    const float hl2 = h11[ub + (size_t)(((32+p)<<6)+q)*C_];
    const float hh2 = h11[ub + (size_t)(((32+p)<<6)+32+q)*C_];
    float yl1[2][2];
    yl1[0][0] = (l2+lh2+hl2+hh2)*0.5f;
    yl1[0][1] = (l2+lh2-hl2-hh2)*0.5f;
    yl1[1][0] = (l2-lh2+hl2-hh2)*0.5f;
    yl1[1][1] = (l2-lh2-hl2+hh2)*0.5f;
    const size_t bstride = (size_t)64*64*C_;
    float v[16];
    #pragma unroll
    for (int di = 0; di < 2; ++di)
        #pragma unroll
        for (int dj = 0; dj < 2; ++dj) {
            const int i1 = (p<<1)+di, j1 = (q<<1)+dj;
            const size_t bb0 = (((size_t)b*3*64 + i1)*64 + j1)*C_ + c;
            const float lh = bands[bb0];
            const float hl = bands[bb0 +   bstride];
            const float hh = bands[bb0 + 2*bstride];
            const float ll = yl1[di][dj];
            v[(2*di+0)*4 + 2*dj+0] = (ll+lh+hl+hh)*0.5f;
            v[(2*di+0)*4 + 2*dj+1] = (ll+lh-hl-hh)*0.5f;
            v[(2*di+1)*4 + 2*dj+0] = (ll-lh+hl-hh)*0.5f;
            v[(2*di+1)*4 + 2*dj+1] = (ll-lh-hl+hh)*0.5f;
        }
    #pragma unroll
    for (int p16 = 0; p16 < 16; ++p16) vb[p16][c] = v[p16];
    __syncthreads();
    {
        const int pp = c >> 3, gg = c & 7;
        float s = 0.f, ss = 0.f;
        #pragma unroll
        for (int i = 0; i < 16; ++i) {
            const float x = vb[pp][gg*16 + i];
            s += x; ss += x*x;
        }
        s += __shfl_xor(s, 1); ss += __shfl_xor(ss, 1);
        s += __shfl_xor(s, 2); ss += __shfl_xor(ss, 2);
        s += __shfl_xor(s, 4); ss += __shfl_xor(ss, 4);
        if (gg == 0) { stat[pp][0] = s; stat[pp][1] = ss; }
    }
    __syncthreads();
    const float gm = gamma[c], bt = beta[c];
    #pragma unroll
    for (int p16 = 0; p16 < 16; ++p16) {
        const int lr = p16 >> 2, lc = p16 & 3;
        const size_t l = (size_t)((p<<2)+lr)*W_ + (q<<2)+lc;
        const float mu  = stat[p16][0] * 0.0078125f;
        const float var = stat[p16][1] * 0.0078125f - mu*mu;
        const float ri  = rsqrtf(var + 1e-5f);
        float y = (v[p16] - mu)*ri*gm + bt;
        const float zv = z[((size_t)b*L_ + l)*C_ + c];
        y *= zv / (1.f + __expf(-zv));
        yout[((size_t)b*L_ + l)*C_ + c] = y;
    }
}

// ============================================================================
extern "C" void kernel_launch(void* const* d_in, const int* in_sizes, int n_in,
                              void* d_out, int out_size, void* d_ws, size_t ws_size,
                              hipStream_t stream) {
    (void)in_sizes; (void)n_in; (void)out_size; (void)ws_size;
    const float* x      = (const float*)d_in[0];
    const float* prompt = (const float*)d_in[1];
    const float* in_w   = (const float*)d_in[2];
    const float* x_w    = (const float*)d_in[3];
    const float* dt_w   = (const float*)d_in[4];
    const float* dt_b   = (const float*)d_in[5];
    const float* A_logs = (const float*)d_in[6];
    const float* Ds     = (const float*)d_in[7];
    const float* gam    = (const float*)d_in[8];
    const float* bet    = (const float*)d_in[9];
    const float* out_w  = (const float*)d_in[10];
    const float* out_b  = (const float*)d_in[11];
    float* wsp   = (float*)d_ws;
    float* xproc = wsp + OFF_XPROC;   // later reused for gated y
    float* z     = wsp + OFF_Z;
    float* bands = wsp + OFF_BANDS;
    float* u     = wsp + OFF_U;
    float* delta = wsp + OFF_DELTA;
    float* Bs    = wsp + OFF_BS;
    float* Cs    = wsp + OFF_CS;
    float* dsum  = wsp + OFF_DSUM;
    float* hend  = wsp + OFF_HEND;
    float* hin   = wsp + OFF_HIN;
    float* h11   = wsp + OFF_H11;
    float* xd    = wsp + OFF_XDBL;
    unsigned short* wq = (unsigned short*)(wsp + OFF_WCVT);
    unsigned short* whi_in  = wq;
    unsigned short* wlo_in  = wq + 32768;
    unsigned short* whi_out = wq + 65536;
    unsigned short* wlo_out = wq + 81920;
    unsigned short* whi_xw  = wq + 98304;
    unsigned short* wlo_xw  = wq + 102400;
    float* out   = (float*)d_out;

    // 0) split weights into bf16 hi/lo
    k_cvt<<<208, 256, 0, stream>>>(in_w, out_w, x_w, wq);
    // 1) in_proj GEMM (MFMA, weights-in-regs, persistent) -> x_proc, z
    k_gemm2<false><<<512, 256, 0, stream>>>(x, whi_in, wlo_in, xproc, z, nullptr, nullptr);
    // 2) 2-level DWT -> bands1 + compact active-region u
    k_dwt<<<4096, 128, 0, stream>>>(xproc, bands, u);
    // 3a) x_dbl = u @ x_proj^T (MFMA)
    k_xdbl<<<128, 256, 0, stream>>>(u, whi_xw, wlo_xw, xd);
    // 3b) delta / Bs / Cs (fully parallel)
    k_dbc<<<8192, 256, 0, stream>>>(xd, prompt, dt_w, dt_b, delta, Bs, Cs);
    // 4) chunked scan: summaries
    k_scan1<<<512, 256, 0, stream>>>(delta, u, Bs, A_logs, dsum, hend);
    // 5) serial combine across chunk boundaries
    k_comb<<<16, 256, 0, stream>>>(dsum, hend, A_logs, dt_b, hin);
    // 6) re-scan with true initial states -> h11
    k_scan2<<<512, 256, 0, stream>>>(delta, u, Bs, Cs, A_logs, Ds, hin, h11);
    // 7) fused inverse DWT + LayerNorm + SiLU gate -> y (xproc buffer)
    k_idwt_ln<<<4096, 128, 0, stream>>>(h11, bands, z, gam, bet, xproc);
    // 8) out_proj GEMM + bias + residual -> d_out
    k_gemm2<true><<<512, 256, 0, stream>>>(xproc, whi_out, wlo_out, out, nullptr, out_b, x);
}